// Round 3
// baseline (426.129 us; speedup 1.0000x reference)
//
#include <hip/hip_runtime.h>

namespace {
constexpr int kB = 16;
constexpr int kMAXLEN = 1024;
constexpr int kPE = 256;
constexpr int kN = 1024;
constexpr int kEMB = 256;
constexpr int kC = 128;
constexpr float kEPS = 1e-5f;

// workspace offsets in floats
constexpr size_t OFF_FEATPART = 0;                       // 16*8*256 = 32768
constexpr size_t OFF_M1       = 32768;                   // m1t transposed: 512*16 = 8192
constexpr size_t OFF_X        = 65536;                   // 16*1024*128 = 2097152
constexpr size_t OFF_QK       = OFF_X   + 2097152;       // q|k, later reused as z
constexpr size_t OFF_TCUR     = OFF_QK  + 2097152;
constexpr size_t OFF_TNEXT    = OFF_TCUR+ 2097152;
constexpr size_t OFF_ATT      = OFF_TNEXT+2097152;       // 16*1024*1024 (also go-partials early)
constexpr size_t OFF_PMAX     = OFF_ATT + 16777216;      // 16*16*1024
constexpr size_t OFF_PSUM     = OFF_PMAX+ 262144;
constexpr size_t OFF_CMAX     = OFF_PSUM+ 262144;        // 16*1024
constexpr size_t OFF_CINV     = OFF_CMAX+ 16384;
// bf16 hi/lo buffers (sizes in float units; each bf16 elem = 0.5 float)
constexpr size_t OFF_ADJH     = OFF_CINV + 16384;        // 16.8M bf16 = 8388608 floats
constexpr size_t OFF_ADJL     = OFF_ADJH + 8388608;
constexpr size_t OFF_XTH      = OFF_ADJL + 8388608;      // 2.1M bf16 = 1048576 floats
constexpr size_t OFF_XTL      = OFF_XTH  + 1048576;
constexpr size_t OFF_END      = OFF_XTL  + 1048576;      // ~178.7 MB

typedef __attribute__((ext_vector_type(8))) short bfrag;
typedef __attribute__((ext_vector_type(4))) float f32x4;

__device__ inline ushort f2bf(float f) {
  unsigned u = __float_as_uint(f);
  unsigned r = (u + 0x7FFFu + ((u >> 16) & 1u)) >> 16;  // RNE
  return (ushort)r;
}
__device__ inline float bf2f(ushort h) { return __uint_as_float(((unsigned)h) << 16); }
} // namespace

// ---- 1. embedding gather partial sums: featpart[b][chunk][e] ----
__global__ __launch_bounds__(256) void k_embsum(const int* __restrict__ data,
                                                const float* __restrict__ emb,
                                                float* __restrict__ featpart) {
  const int b = blockIdx.x, ch = blockIdx.y;   // 16 x 8
  const int e = threadIdx.x;                   // 256
  const int* row = data + b * (kMAXLEN + kPE) + ch * 128;
  float acc = 0.f;
#pragma unroll 4
  for (int l = 0; l < 128; ++l) {
    acc += emb[(size_t)row[l] * kEMB + e];
  }
  featpart[((b * 8 + ch) << 8) + e] = acc;
}

// ---- 2. BN over batch of concat[feat, inp2] -> m1t (512,16) TRANSPOSED ----
__global__ __launch_bounds__(512) void k_bn_feat(const float* __restrict__ featpart,
                                                 const int* __restrict__ data,
                                                 const float* __restrict__ g1,
                                                 const float* __restrict__ b1,
                                                 float* __restrict__ m1t) {
  const int j = threadIdx.x;  // 0..511 (feature index k)
  float v[kB];
  if (j < kPE) {
    const float pe = sinf((float)j);
#pragma unroll
    for (int b = 0; b < kB; ++b) {
      float s = 0.f;
      for (int ch = 0; ch < 8; ++ch) s += featpart[((b * 8 + ch) << 8) + j];
      v[b] = s * (1.f / 1024.f) + pe;
    }
  } else {
    const int e = j - kPE;
    const float pe = sinf((float)e);
#pragma unroll
    for (int b = 0; b < kB; ++b)
      v[b] = (float)data[b * (kMAXLEN + kPE) + kMAXLEN + e] + pe;
  }
  float s = 0.f;
#pragma unroll
  for (int b = 0; b < kB; ++b) s += v[b];
  const float mean = s * (1.f / kB);
  float s2 = 0.f;
#pragma unroll
  for (int b = 0; b < kB; ++b) { float d = v[b] - mean; s2 += d * d; }
  const float inv = rsqrtf(s2 * (1.f / kB) + kEPS);
  const float g = g1[j], bb = b1[j];
#pragma unroll
  for (int b = 0; b < kB; ++b) m1t[j * kB + b] = (v[b] - mean) * inv * g + bb;
}

// ---- 3a. split-K GEMM: part[kb][b][col] = sum_{k in kb} m1t[k][b]*w_go[k][col] ----
__global__ __launch_bounds__(256) void k_go_gemm2(const float* __restrict__ m1t,
                                                  const float* __restrict__ w_go,
                                                  float* __restrict__ part) {
  const int c0 = blockIdx.x * 1024 + threadIdx.x * 4;   // column base
  const int k0 = blockIdx.y * 128;                      // k-slice base
  float4 acc[kB];
#pragma unroll
  for (int b = 0; b < kB; ++b) acc[b] = make_float4(0.f, 0.f, 0.f, 0.f);
#pragma unroll 4
  for (int k = 0; k < 128; ++k) {
    const float4 w = *reinterpret_cast<const float4*>(&w_go[(size_t)(k0 + k) * 65536 + c0]);
    const float* mrow = m1t + (size_t)(k0 + k) * kB;   // uniform address -> s_load
#pragma unroll
    for (int b = 0; b < kB; ++b) {
      const float m = mrow[b];
      acc[b].x += m * w.x; acc[b].y += m * w.y;
      acc[b].z += m * w.z; acc[b].w += m * w.w;
    }
  }
  const size_t kb16 = (size_t)blockIdx.y * kB;
#pragma unroll
  for (int b = 0; b < kB; ++b) {
    *reinterpret_cast<float4*>(&part[(kb16 + b) * 65536 + c0]) = acc[b];
  }
}

// ---- 3b. reduce partials + bias + relu -> x[...,0:64] ----
__global__ __launch_bounds__(256) void k_go_reduce(const float* __restrict__ part,
                                                   const float* __restrict__ b_go,
                                                   float* __restrict__ x) {
  const int g = blockIdx.x * 256 + threadIdx.x;  // 0..262143 float4 ids
  const int b = g >> 14;                          // /16384
  const int cw = g & 16383;
  const int col = cw * 4;
  float4 a = *reinterpret_cast<const float4*>(&part[(size_t)b * 65536 + col]);
#pragma unroll
  for (int kb = 1; kb < 4; ++kb) {
    float4 p = *reinterpret_cast<const float4*>(&part[(size_t)(kb * kB + b) * 65536 + col]);
    a.x += p.x; a.y += p.y; a.z += p.z; a.w += p.w;
  }
  const float4 bg = *reinterpret_cast<const float4*>(&b_go[col]);
  a.x = fmaxf(a.x + bg.x, 0.f); a.y = fmaxf(a.y + bg.y, 0.f);
  a.z = fmaxf(a.z + bg.z, 0.f); a.w = fmaxf(a.w + bg.w, 0.f);
  const int n = col >> 6, c = col & 63;
  *reinterpret_cast<float4*>(&x[((size_t)(b * kN + n)) * kC + c]) = a;
}

// ---- 4. per-node BN over (b,c); fills nf half of x, normalizes in place ----
__global__ __launch_bounds__(256) void k_nf_bn(const float* __restrict__ nf,
                                               const float* __restrict__ g3,
                                               const float* __restrict__ b3,
                                               float* __restrict__ x) {
  const int n = blockIdx.x;
  const int tid = threadIdx.x;
  float s = 0.f, s2 = 0.f;
#pragma unroll
  for (int it = 0; it < 4; ++it) {
    int e = it * 256 + tid;
    int b = e >> 6, c = e & 63;
    float v = x[((size_t)(b * kN + n)) * kC + c];
    s += v; s2 += v * v;
  }
  if (tid < 64) {
    float v = nf[n * 64 + tid];
    s += 16.f * v; s2 += 16.f * v * v;
  }
  for (int o = 32; o > 0; o >>= 1) { s += __shfl_down(s, o); s2 += __shfl_down(s2, o); }
  __shared__ float ls[4], ls2[4];
  __shared__ float sscale, sshift;
  const int w = tid >> 6;
  if ((tid & 63) == 0) { ls[w] = s; ls2[w] = s2; }
  __syncthreads();
  if (tid == 0) {
    float S = ls[0] + ls[1] + ls[2] + ls[3];
    float S2 = ls2[0] + ls2[1] + ls2[2] + ls2[3];
    float mean = S * (1.f / 2048.f);
    float var = S2 * (1.f / 2048.f) - mean * mean;
    var = fmaxf(var, 0.f);
    float inv = rsqrtf(var + kEPS);
    float gg = g3[n];
    sscale = inv * gg;
    sshift = b3[n] - mean * inv * gg;
  }
  __syncthreads();
  const float scale = sscale, shift = sshift;
#pragma unroll
  for (int it = 0; it < 8; ++it) {
    int e = it * 256 + tid;
    int b = e >> 7, c = e & 127;
    size_t idx = ((size_t)(b * kN + n)) * kC + c;
    float v = (c < 64) ? x[idx] : nf[n * 64 + (c - 64)];
    x[idx] = v * scale + shift;
  }
}

// ---- 5. qk = x @ [wq|wk] : (16384,128)@(128,128) ----
__global__ __launch_bounds__(256) void k_qk(const float* __restrict__ x,
                                            const float* __restrict__ wq,
                                            const float* __restrict__ wk,
                                            float* __restrict__ qk) {
  __shared__ float a_s[32 * 68];
  __shared__ float w_s[32 * 128];
  const int row0 = blockIdx.x * 32;
  const int tid = threadIdx.x;
  const int tr = tid >> 5, tc = tid & 31;
  const int r0 = tr * 4, c0 = tc * 4;
  float acc[4][4] = {};
  for (int kc = 0; kc < 4; ++kc) {
    const int k0 = kc * 32;
    __syncthreads();
    {  // stage A: 32 rows x 32 k = 256 float4, one per thread
      int r = tid >> 3, kk4 = tid & 7;
      float4 v = *reinterpret_cast<const float4*>(&x[(size_t)(row0 + r) * kC + k0 + kk4 * 4]);
      *reinterpret_cast<float4*>(&a_s[r * 68 + kk4 * 4]) = v;
    }
    for (int it = 0; it < 16; ++it) {  // stage W: 32x128 scalars
      int e = it * 256 + tid;
      int kk = e >> 7, h2 = e & 127;
      int c = k0 + kk;
      float v = (h2 < 64) ? wq[c * 64 + h2] : wk[c * 64 + (h2 - 64)];
      w_s[kk * 128 + h2] = v;
    }
    __syncthreads();
#pragma unroll 8
    for (int k = 0; k < 32; ++k) {
      float a[4];
#pragma unroll
      for (int i = 0; i < 4; ++i) a[i] = a_s[(r0 + i) * 68 + k];
      float4 b4 = *reinterpret_cast<float4*>(&w_s[k * 128 + c0]);
      float bj[4] = {b4.x, b4.y, b4.z, b4.w};
#pragma unroll
      for (int i = 0; i < 4; ++i)
#pragma unroll
        for (int j = 0; j < 4; ++j) acc[i][j] += a[i] * bj[j];
    }
  }
#pragma unroll
  for (int i = 0; i < 4; ++i) {
    float4 o = {acc[i][0], acc[i][1], acc[i][2], acc[i][3]};
    *reinterpret_cast<float4*>(&qk[(size_t)(row0 + r0 + i) * kC + c0]) = o;
  }
}

// ---- 6. att[b,n,m] = q.k / 8 : 64x64 tiles ----
__global__ __launch_bounds__(256) void k_att(const float* __restrict__ qk,
                                             float* __restrict__ att) {
  const int mt = blockIdx.x, nt = blockIdx.y, b = blockIdx.z;
  __shared__ float qs[64 * 65], ks[64 * 65];
  const int tid = threadIdx.x;
  for (int it = 0; it < 16; ++it) {
    int e = it * 256 + tid;
    int r = e >> 6, h = e & 63;
    qs[r * 65 + h] = qk[(size_t)(b * kN + nt * 64 + r) * kC + h];
    ks[r * 65 + h] = qk[(size_t)(b * kN + mt * 64 + r) * kC + 64 + h];
  }
  __syncthreads();
  const int tr = tid >> 4, tc = tid & 15;
  const int r0 = tr * 4, c0 = tc * 4;
  float acc[4][4] = {};
#pragma unroll 8
  for (int k = 0; k < 64; ++k) {
    float a[4], bb[4];
#pragma unroll
    for (int i = 0; i < 4; ++i) a[i] = qs[(r0 + i) * 65 + k];
#pragma unroll
    for (int j = 0; j < 4; ++j) bb[j] = ks[(c0 + j) * 65 + k];
#pragma unroll
    for (int i = 0; i < 4; ++i)
#pragma unroll
      for (int j = 0; j < 4; ++j) acc[i][j] += a[i] * bb[j];
  }
  const float sc = 0.125f;  // 1/sqrt(64)
#pragma unroll
  for (int i = 0; i < 4; ++i) {
    float4 o = {acc[i][0] * sc, acc[i][1] * sc, acc[i][2] * sc, acc[i][3] * sc};
    *reinterpret_cast<float4*>(
        &att[(size_t)(b * kN + nt * 64 + r0 + i) * kN + mt * 64 + c0]) = o;
  }
}

// ---- 7a. column-softmax partial stats (online max/sum over n-chunks) ----
__global__ __launch_bounds__(256) void k_soft_stat(const float* __restrict__ att,
                                                   float* __restrict__ pmax,
                                                   float* __restrict__ psum) {
  const int b = blockIdx.x, ch = blockIdx.y;  // 16 x 16
  const int tid = threadIdx.x;
  const int m0 = tid * 4;
  float mx0 = -1e30f, mx1 = -1e30f, mx2 = -1e30f, mx3 = -1e30f;
  float sm0 = 0.f, sm1 = 0.f, sm2 = 0.f, sm3 = 0.f;
#pragma unroll 2
  for (int n = ch * 64; n < ch * 64 + 64; ++n) {
    float4 v = *reinterpret_cast<const float4*>(&att[(size_t)(b * kN + n) * kN + m0]);
    float nm;
    nm = fmaxf(mx0, v.x); sm0 = sm0 * __expf(mx0 - nm) + __expf(v.x - nm); mx0 = nm;
    nm = fmaxf(mx1, v.y); sm1 = sm1 * __expf(mx1 - nm) + __expf(v.y - nm); mx1 = nm;
    nm = fmaxf(mx2, v.z); sm2 = sm2 * __expf(mx2 - nm) + __expf(v.z - nm); mx2 = nm;
    nm = fmaxf(mx3, v.w); sm3 = sm3 * __expf(mx3 - nm) + __expf(v.w - nm); mx3 = nm;
  }
  const size_t base = (size_t)(b * 16 + ch) * kN + m0;
  float4 pm = {mx0, mx1, mx2, mx3};
  float4 ps = {sm0, sm1, sm2, sm3};
  *reinterpret_cast<float4*>(&pmax[base]) = pm;
  *reinterpret_cast<float4*>(&psum[base]) = ps;
}

// ---- 7b. combine chunk stats -> colmax, 1/colsum ----
__global__ __launch_bounds__(256) void k_soft_comb(const float* __restrict__ pmax,
                                                   const float* __restrict__ psum,
                                                   float* __restrict__ cmax,
                                                   float* __restrict__ cinv) {
  const int i = blockIdx.x * 256 + threadIdx.x;  // 16384
  const int b = i >> 10, m = i & 1023;
  float M = -1e30f;
#pragma unroll
  for (int c = 0; c < 16; ++c) M = fmaxf(M, pmax[(size_t)(b * 16 + c) * kN + m]);
  float S = 0.f;
#pragma unroll
  for (int c = 0; c < 16; ++c)
    S += psum[(size_t)(b * 16 + c) * kN + m] * __expf(pmax[(size_t)(b * 16 + c) * kN + m] - M);
  cmax[i] = M;
  cinv[i] = 1.f / S;
}

// ---- 7c-new. adj = go_adj + softmax -> bf16 hi/lo split ----
__global__ __launch_bounds__(256) void k_adj_split(const float* __restrict__ att,
                                                   const float* __restrict__ go_adj,
                                                   const float* __restrict__ cmax,
                                                   const float* __restrict__ cinv,
                                                   ushort* __restrict__ adj_hi,
                                                   ushort* __restrict__ adj_lo) {
  const size_t f4 = (size_t)blockIdx.x * 256 + threadIdx.x;  // 4,194,304
  const size_t e = f4 * 4;
  const int b = (int)(e >> 20);
  const int rem = (int)(e & 1048575);
  const int n = rem >> 10, m = rem & 1023;
  float4 v = *reinterpret_cast<const float4*>(&att[e]);
  float4 ga = *reinterpret_cast<const float4*>(&go_adj[n * kN + m]);
  float4 M = *reinterpret_cast<const float4*>(&cmax[b * kN + m]);
  float4 I = *reinterpret_cast<const float4*>(&cinv[b * kN + m]);
  float a0 = ga.x + __expf(v.x - M.x) * I.x;
  float a1 = ga.y + __expf(v.y - M.y) * I.y;
  float a2 = ga.z + __expf(v.z - M.z) * I.z;
  float a3 = ga.w + __expf(v.w - M.w) * I.w;
  ushort4 h, l;
  h.x = f2bf(a0); l.x = f2bf(a0 - bf2f(h.x));
  h.y = f2bf(a1); l.y = f2bf(a1 - bf2f(h.y));
  h.z = f2bf(a2); l.z = f2bf(a2 - bf2f(h.z));
  h.w = f2bf(a3); l.w = f2bf(a3 - bf2f(h.w));
  *reinterpret_cast<ushort4*>(&adj_hi[e]) = h;
  *reinterpret_cast<ushort4*>(&adj_lo[e]) = l;
}

// ---- 7c-old. adj = go_adj + softmax (in place on att), fp32 fallback ----
__global__ __launch_bounds__(256) void k_adj(float* __restrict__ att,
                                             const float* __restrict__ go_adj,
                                             const float* __restrict__ cmax,
                                             const float* __restrict__ cinv) {
  const size_t f4 = (size_t)blockIdx.x * 256 + threadIdx.x;
  const size_t e = f4 * 4;
  const int b = (int)(e >> 20);
  const int rem = (int)(e & 1048575);
  const int n = rem >> 10, m = rem & 1023;
  float4 v = *reinterpret_cast<float4*>(&att[e]);
  float4 ga = *reinterpret_cast<const float4*>(&go_adj[n * kN + m]);
  float4 M = *reinterpret_cast<const float4*>(&cmax[b * kN + m]);
  float4 I = *reinterpret_cast<const float4*>(&cinv[b * kN + m]);
  v.x = ga.x + __expf(v.x - M.x) * I.x;
  v.y = ga.y + __expf(v.y - M.y) * I.y;
  v.z = ga.z + __expf(v.z - M.z) * I.z;
  v.w = ga.w + __expf(v.w - M.w) * I.w;
  *reinterpret_cast<float4*>(&att[e]) = v;
}

// ---- T. transpose+split: src f32 [16][1024][128] -> xt_hi/lo bf16 [16][128][1024] ----
__global__ __launch_bounds__(256) void k_split_t(const float* __restrict__ src,
                                                 ushort* __restrict__ xt_hi,
                                                 ushort* __restrict__ xt_lo) {
  const int nt = blockIdx.x, b = blockIdx.y;  // 16 x 16 (64-row n tiles)
  __shared__ float tile[64][132];
  const int tid = threadIdx.x;
#pragma unroll
  for (int it = 0; it < 8; ++it) {
    int e = it * 256 + tid;
    int r = e >> 5, c4 = e & 31;
    float4 v = *reinterpret_cast<const float4*>(&src[(size_t)(b * kN + nt * 64 + r) * kC + c4 * 4]);
    *reinterpret_cast<float4*>(&tile[r][c4 * 4]) = v;
  }
  __syncthreads();
  const int c = tid & 127, half = tid >> 7;
  const int n0 = half * 32;
  const size_t obase = (size_t)(b * kC + c) * kN + nt * 64 + n0;
#pragma unroll
  for (int q = 0; q < 4; ++q) {
    ushort hs[8], ls[8];
#pragma unroll
    for (int j = 0; j < 8; ++j) {
      float v = tile[n0 + q * 8 + j][c];
      ushort h = f2bf(v);
      hs[j] = h;
      ls[j] = f2bf(v - bf2f(h));
    }
    *reinterpret_cast<uint4*>(&xt_hi[obase + q * 8]) = *reinterpret_cast<uint4*>(hs);
    *reinterpret_cast<uint4*>(&xt_lo[obase + q * 8]) = *reinterpret_cast<uint4*>(ls);
  }
}

// ---- 8-new. Y = alpha * adj @ X (- Zsub), bf16 hi/lo split MFMA ----
// grid (16 rowblocks, 16 b), block 1024 = 16 waves. Wave: 16 rows x 32 cols.
__global__ __launch_bounds__(1024) void k_adjmm_mfma(const ushort* __restrict__ adj_hi,
                                                     const ushort* __restrict__ adj_lo,
                                                     const ushort* __restrict__ xt_hi,
                                                     const ushort* __restrict__ xt_lo,
                                                     const float* __restrict__ Zsub,
                                                     float* __restrict__ Y, float alpha) {
  const int b = blockIdx.y, rb = blockIdx.x;
  const int tid = threadIdx.x;
  const int w = tid >> 6, lane = tid & 63;
  const int wr = w >> 2, wc = w & 3;            // row sub-block / col block
  const int row = rb * 64 + wr * 16 + (lane & 15);
  const int koff = (lane >> 4) * 8;
  const size_t abase = ((size_t)(b * kN + row)) * kN + koff;
  const int col0 = wc * 32 + (lane & 15);
  const size_t bbase0 = ((size_t)(b * kC + col0)) * kN + koff;
  const size_t bbase1 = bbase0 + 16 * (size_t)kN;

  f32x4 acc0 = {0.f, 0.f, 0.f, 0.f};
  f32x4 acc1 = {0.f, 0.f, 0.f, 0.f};
#pragma unroll 2
  for (int ks = 0; ks < 32; ++ks) {
    const int kd = ks * 32;
    bfrag ah  = *reinterpret_cast<const bfrag*>(adj_hi + abase + kd);
    bfrag al  = *reinterpret_cast<const bfrag*>(adj_lo + abase + kd);
    bfrag bh0 = *reinterpret_cast<const bfrag*>(xt_hi + bbase0 + kd);
    bfrag bl0 = *reinterpret_cast<const bfrag*>(xt_lo + bbase0 + kd);
    bfrag bh1 = *reinterpret_cast<const bfrag*>(xt_hi + bbase1 + kd);
    bfrag bl1 = *reinterpret_cast<const bfrag*>(xt_lo + bbase1 + kd);
    acc0 = __builtin_amdgcn_mfma_f32_16x16x32_bf16(ah, bh0, acc0, 0, 0, 0);
    acc1 = __builtin_amdgcn_mfma_f32_16x16x32_bf16(ah, bh1, acc1, 0, 0, 0);
    acc0 = __builtin_amdgcn_mfma_f32_16x16x32_bf16(ah, bl0, acc0, 0, 0, 0);
    acc1 = __builtin_amdgcn_mfma_f32_16x16x32_bf16(ah, bl1, acc1, 0, 0, 0);
    acc0 = __builtin_amdgcn_mfma_f32_16x16x32_bf16(al, bh0, acc0, 0, 0, 0);
    acc1 = __builtin_amdgcn_mfma_f32_16x16x32_bf16(al, bh1, acc1, 0, 0, 0);
  }
  // C/D layout: col = lane&15, row = (lane>>4)*4 + i
  const int orow = rb * 64 + wr * 16 + (lane >> 4) * 4;
  const int ocol = wc * 32 + (lane & 15);
#pragma unroll
  for (int i = 0; i < 4; ++i) {
    size_t idx = ((size_t)(b * kN + orow + i)) * kC + ocol;
    float v0 = alpha * acc0[i];
    float v1 = alpha * acc1[i];
    if (Zsub) {
      v0 -= Zsub[idx];
      v1 -= Zsub[idx + 16];
    }
    Y[idx] = v0;
    Y[idx + 16] = v1;
  }
}

// ---- 8-old. fp32 fallback adjmm ----
__global__ __launch_bounds__(256) void k_adjmm(const float* __restrict__ adj,
                                               const float* __restrict__ X,
                                               const float* __restrict__ Zsub,
                                               float* __restrict__ Y, float alpha) {
  const int nt = blockIdx.x, b = blockIdx.y;  // 32 x 16
  __shared__ float a_s[32 * 68];
  __shared__ float x_s[64 * 128];
  const int tid = threadIdx.x;
  const int tr = tid >> 5, tc = tid & 31;
  const int r0 = tr * 4, c0 = tc * 4;
  float acc[4][4] = {};
  const float* adjb = adj + (size_t)b * kN * kN;
  for (int kt = 0; kt < 16; ++kt) {
    const int k0 = kt * 64;
    __syncthreads();
#pragma unroll
    for (int it = 0; it < 2; ++it) {
      int e4 = it * 256 + tid;
      int r = e4 >> 4, kk4 = e4 & 15;
      float4 v = *reinterpret_cast<const float4*>(&adjb[(size_t)(nt * 32 + r) * kN + k0 + kk4 * 4]);
      *reinterpret_cast<float4*>(&a_s[r * 68 + kk4 * 4]) = v;
    }
#pragma unroll
    for (int it = 0; it < 8; ++it) {
      int e4 = it * 256 + tid;
      int k = e4 >> 5, c4 = e4 & 31;
      float4 v = *reinterpret_cast<const float4*>(&X[(size_t)(b * kN + k0 + k) * kC + c4 * 4]);
      *reinterpret_cast<float4*>(&x_s[k * 128 + c4 * 4]) = v;
    }
    __syncthreads();
#pragma unroll 8
    for (int k = 0; k < 64; ++k) {
      float a[4];
#pragma unroll
      for (int i = 0; i < 4; ++i) a[i] = a_s[(r0 + i) * 68 + k];
      float4 b4 = *reinterpret_cast<float4*>(&x_s[k * 128 + c0]);
      float bj[4] = {b4.x, b4.y, b4.z, b4.w};
#pragma unroll
      for (int i = 0; i < 4; ++i)
#pragma unroll
        for (int j = 0; j < 4; ++j) acc[i][j] += a[i] * bj[j];
    }
  }
#pragma unroll
  for (int i = 0; i < 4; ++i) {
    size_t idx = (size_t)(b * kN + nt * 32 + r0 + i) * kC + c0;
    float4 o = {alpha * acc[i][0], alpha * acc[i][1], alpha * acc[i][2], alpha * acc[i][3]};
    if (Zsub) {
      float4 z = *reinterpret_cast<const float4*>(&Zsub[idx]);
      o.x -= z.x; o.y -= z.y; o.z -= z.z; o.w -= z.w;
    }
    *reinterpret_cast<float4*>(&Y[idx]) = o;
  }
}

// ---- 9. z = x@th0 + tcur@th1 + tnext@th2 + x ----
__global__ __launch_bounds__(256) void k_theta(const float* __restrict__ x,
                                               const float* __restrict__ tcur,
                                               const float* __restrict__ tnext,
                                               const float* __restrict__ theta,
                                               float* __restrict__ z) {
  __shared__ float a_s[32 * 68];
  __shared__ float w_s[32 * 128];
  const int row0 = blockIdx.x * 32;
  const int tid = threadIdx.x;
  const int tr = tid >> 5, tc = tid & 31;
  const int r0 = tr * 4, c0 = tc * 4;
  float acc[4][4] = {};
  const float* srcs[3] = {x, tcur, tnext};
  for (int s = 0; s < 3; ++s) {
    const float* A = srcs[s];
    for (int kc = 0; kc < 4; ++kc) {
      const int k0 = kc * 32;
      __syncthreads();
      {
        int r = tid >> 3, kk4 = tid & 7;
        float4 v = *reinterpret_cast<const float4*>(&A[(size_t)(row0 + r) * kC + k0 + kk4 * 4]);
        *reinterpret_cast<float4*>(&a_s[r * 68 + kk4 * 4]) = v;
      }
#pragma unroll
      for (int it = 0; it < 4; ++it) {
        int e4 = it * 256 + tid;
        int kk = e4 >> 5, d4 = e4 & 31;
        float4 v = *reinterpret_cast<const float4*>(
            &theta[(size_t)s * 16384 + (size_t)(k0 + kk) * kC + d4 * 4]);
        *reinterpret_cast<float4*>(&w_s[kk * 128 + d4 * 4]) = v;
      }
      __syncthreads();
#pragma unroll 8
      for (int k = 0; k < 32; ++k) {
        float a[4];
#pragma unroll
        for (int i = 0; i < 4; ++i) a[i] = a_s[(r0 + i) * 68 + k];
        float4 b4 = *reinterpret_cast<float4*>(&w_s[k * 128 + c0]);
        float bj[4] = {b4.x, b4.y, b4.z, b4.w};
#pragma unroll
        for (int i = 0; i < 4; ++i)
#pragma unroll
          for (int j = 0; j < 4; ++j) acc[i][j] += a[i] * bj[j];
      }
    }
  }
#pragma unroll
  for (int i = 0; i < 4; ++i) {
    size_t idx = (size_t)(row0 + r0 + i) * kC + c0;
    float4 xv = *reinterpret_cast<const float4*>(&x[idx]);
    float4 o = {acc[i][0] + xv.x, acc[i][1] + xv.y, acc[i][2] + xv.z, acc[i][3] + xv.w};
    *reinterpret_cast<float4*>(&z[idx]) = o;
  }
}

// ---- 10. per-node BN + relu + dot(w_out) -> out (16,1024) ----
__global__ __launch_bounds__(256) void k_final(const float* __restrict__ z,
                                               const float* __restrict__ g4,
                                               const float* __restrict__ b4v,
                                               const float* __restrict__ w_out,
                                               const float* __restrict__ b_out,
                                               float* __restrict__ out) {
  const int n = blockIdx.x;
  const int tid = threadIdx.x;
  float s = 0.f, s2 = 0.f;
#pragma unroll
  for (int it = 0; it < 8; ++it) {
    int e = it * 256 + tid;
    int b = e >> 7, c = e & 127;
    float v = z[(size_t)(b * kN + n) * kC + c];
    s += v; s2 += v * v;
  }
  for (int o = 32; o > 0; o >>= 1) { s += __shfl_down(s, o); s2 += __shfl_down(s2, o); }
  __shared__ float ls[4], ls2[4];
  __shared__ float sscale, sshift;
  const int w = tid >> 6;
  if ((tid & 63) == 0) { ls[w] = s; ls2[w] = s2; }
  __syncthreads();
  if (tid == 0) {
    float S = ls[0] + ls[1] + ls[2] + ls[3];
    float S2 = ls2[0] + ls2[1] + ls2[2] + ls2[3];
    float mean = S * (1.f / 2048.f);
    float var = S2 * (1.f / 2048.f) - mean * mean;
    var = fmaxf(var, 0.f);
    float inv = rsqrtf(var + kEPS);
    float gg = g4[n];
    sscale = inv * gg;
    sshift = b4v[n] - mean * inv * gg;
  }
  __syncthreads();
  const float scale = sscale, shift = sshift;
  const int b = tid >> 4, c0 = (tid & 15) * 8;
  float p = 0.f;
#pragma unroll
  for (int j = 0; j < 8; ++j) {
    float v = z[(size_t)(b * kN + n) * kC + c0 + j] * scale + shift;
    v = fmaxf(v, 0.f);
    p += v * w_out[c0 + j];
  }
  for (int o = 8; o > 0; o >>= 1) p += __shfl_down(p, o, 16);
  if ((tid & 15) == 0) out[b * kN + n] = p + b_out[0];
}

extern "C" void kernel_launch(void* const* d_in, const int* in_sizes, int n_in,
                              void* d_out, int out_size, void* d_ws, size_t ws_size,
                              hipStream_t stream) {
  const int*   data = (const int*)d_in[0];
  const float* node_features = (const float*)d_in[1];
  const float* go_adj = (const float*)d_in[2];
  const float* emb  = (const float*)d_in[4];
  const float* w_go = (const float*)d_in[5];
  const float* b_go = (const float*)d_in[6];
  const float* wq   = (const float*)d_in[7];
  const float* wk   = (const float*)d_in[8];
  const float* theta= (const float*)d_in[9];
  const float* g1   = (const float*)d_in[10];
  const float* b1   = (const float*)d_in[11];
  const float* g3   = (const float*)d_in[12];
  const float* b3   = (const float*)d_in[13];
  const float* g4   = (const float*)d_in[14];
  const float* b4   = (const float*)d_in[15];
  const float* w_out= (const float*)d_in[16];
  const float* b_out= (const float*)d_in[17];

  float* ws = (float*)d_ws;
  float* featpart = ws + OFF_FEATPART;
  float* m1t   = ws + OFF_M1;
  float* x     = ws + OFF_X;
  float* qk    = ws + OFF_QK;   // reused as z later
  float* tcur  = ws + OFF_TCUR;
  float* tnext = ws + OFF_TNEXT;
  float* att   = ws + OFF_ATT;  // go-partials alias this region early
  float* pmax  = ws + OFF_PMAX;
  float* psum  = ws + OFF_PSUM;
  float* cmax  = ws + OFF_CMAX;
  float* cinv  = ws + OFF_CINV;
  ushort* adj_hi = (ushort*)(ws + OFF_ADJH);
  ushort* adj_lo = (ushort*)(ws + OFF_ADJL);
  ushort* xt_hi  = (ushort*)(ws + OFF_XTH);
  ushort* xt_lo  = (ushort*)(ws + OFF_XTL);

  const bool mfma_path = ws_size >= OFF_END * sizeof(float);

  k_embsum<<<dim3(16, 8), 256, 0, stream>>>(data, emb, featpart);
  k_bn_feat<<<1, 512, 0, stream>>>(featpart, data, g1, b1, m1t);
  k_go_gemm2<<<dim3(64, 4), 256, 0, stream>>>(m1t, w_go, att /* partials */);
  k_go_reduce<<<1024, 256, 0, stream>>>(att /* partials */, b_go, x);
  k_nf_bn<<<1024, 256, 0, stream>>>(node_features, g3, b3, x);
  k_qk<<<512, 256, 0, stream>>>(x, wq, wk, qk);
  k_att<<<dim3(16, 16, 16), 256, 0, stream>>>(qk, att);
  k_soft_stat<<<dim3(16, 16), 256, 0, stream>>>(att, pmax, psum);
  k_soft_comb<<<64, 256, 0, stream>>>(pmax, psum, cmax, cinv);
  if (mfma_path) {
    k_adj_split<<<16384, 256, 0, stream>>>(att, go_adj, cmax, cinv, adj_hi, adj_lo);
    k_split_t<<<dim3(16, 16), 256, 0, stream>>>(x, xt_hi, xt_lo);
    k_adjmm_mfma<<<dim3(16, 16), 1024, 0, stream>>>(adj_hi, adj_lo, xt_hi, xt_lo,
                                                    nullptr, tcur, 1.0f);
    k_split_t<<<dim3(16, 16), 256, 0, stream>>>(tcur, xt_hi, xt_lo);
    k_adjmm_mfma<<<dim3(16, 16), 1024, 0, stream>>>(adj_hi, adj_lo, xt_hi, xt_lo,
                                                    x, tnext, 2.0f);
  } else {
    k_adj<<<16384, 256, 0, stream>>>(att, go_adj, cmax, cinv);
    k_adjmm<<<dim3(32, 16), 256, 0, stream>>>(att, x, nullptr, tcur, 1.0f);
    k_adjmm<<<dim3(32, 16), 256, 0, stream>>>(att, tcur, x, tnext, 2.0f);
  }
  k_theta<<<512, 256, 0, stream>>>(x, tcur, tnext, theta, qk /* z */);
  k_final<<<1024, 256, 0, stream>>>(qk, g4, b4, w_out, b_out, (float*)d_out);
}

// Round 4
// 300.206 us; speedup vs baseline: 1.4195x; 1.4195x over previous
//
#include <hip/hip_runtime.h>

namespace {
constexpr int kB = 16;
constexpr int kMAXLEN = 1024;
constexpr int kPE = 256;
constexpr int kN = 1024;
constexpr int kEMB = 256;
constexpr int kC = 128;
constexpr float kEPS = 1e-5f;

// workspace offsets in floats
constexpr size_t OFF_FEATPART = 0;                       // 16*8*256 = 32768
constexpr size_t OFF_M1       = 32768;                   // m1t transposed: 512*16 = 8192
constexpr size_t OFF_X        = 65536;                   // 16*1024*128 = 2097152
constexpr size_t OFF_QK       = OFF_X   + 2097152;       // q|k, later reused as z
constexpr size_t OFF_TCUR     = OFF_QK  + 2097152;
constexpr size_t OFF_TNEXT    = OFF_TCUR+ 2097152;
constexpr size_t OFF_ATT      = OFF_TNEXT+2097152;       // 16*1024*1024 (also go-partials early)
constexpr size_t OFF_PMAX     = OFF_ATT + 16777216;      // 16*16*1024
constexpr size_t OFF_PSUM     = OFF_PMAX+ 262144;
constexpr size_t OFF_CMAX     = OFF_PSUM+ 262144;        // 16*1024
constexpr size_t OFF_CINV     = OFF_CMAX+ 16384;
// bf16 hi/lo buffers (sizes in float units; each bf16 elem = 0.5 float)
constexpr size_t OFF_ADJH     = OFF_CINV + 16384;        // 16.8M bf16 = 8388608 floats
constexpr size_t OFF_ADJL     = OFF_ADJH + 8388608;
constexpr size_t OFF_XTH      = OFF_ADJL + 8388608;      // 2.1M bf16 = 1048576 floats
constexpr size_t OFF_XTL      = OFF_XTH  + 1048576;
constexpr size_t OFF_END      = OFF_XTL  + 1048576;      // ~178.7 MB

typedef __attribute__((ext_vector_type(8))) short bfrag;
typedef __attribute__((ext_vector_type(4))) float f32x4;

__device__ inline ushort f2bf(float f) {
  unsigned u = __float_as_uint(f);
  unsigned r = (u + 0x7FFFu + ((u >> 16) & 1u)) >> 16;  // RNE
  return (ushort)r;
}
__device__ inline float bf2f(ushort h) { return __uint_as_float(((unsigned)h) << 16); }
} // namespace

// ---- 1. embedding gather partial sums: featpart[b][chunk][e] ----
__global__ __launch_bounds__(256) void k_embsum(const int* __restrict__ data,
                                                const float* __restrict__ emb,
                                                float* __restrict__ featpart) {
  const int b = blockIdx.x, ch = blockIdx.y;   // 16 x 8
  const int e = threadIdx.x;                   // 256
  const int* row = data + b * (kMAXLEN + kPE) + ch * 128;
  float acc = 0.f;
#pragma unroll 4
  for (int l = 0; l < 128; ++l) {
    acc += emb[(size_t)row[l] * kEMB + e];
  }
  featpart[((b * 8 + ch) << 8) + e] = acc;
}

// ---- 2. BN over batch of concat[feat, inp2] -> m1t (512,16) TRANSPOSED ----
__global__ __launch_bounds__(512) void k_bn_feat(const float* __restrict__ featpart,
                                                 const int* __restrict__ data,
                                                 const float* __restrict__ g1,
                                                 const float* __restrict__ b1,
                                                 float* __restrict__ m1t) {
  const int j = threadIdx.x;  // 0..511 (feature index k)
  float v[kB];
  if (j < kPE) {
    const float pe = sinf((float)j);
#pragma unroll
    for (int b = 0; b < kB; ++b) {
      float s = 0.f;
      for (int ch = 0; ch < 8; ++ch) s += featpart[((b * 8 + ch) << 8) + j];
      v[b] = s * (1.f / 1024.f) + pe;
    }
  } else {
    const int e = j - kPE;
    const float pe = sinf((float)e);
#pragma unroll
    for (int b = 0; b < kB; ++b)
      v[b] = (float)data[b * (kMAXLEN + kPE) + kMAXLEN + e] + pe;
  }
  float s = 0.f;
#pragma unroll
  for (int b = 0; b < kB; ++b) s += v[b];
  const float mean = s * (1.f / kB);
  float s2 = 0.f;
#pragma unroll
  for (int b = 0; b < kB; ++b) { float d = v[b] - mean; s2 += d * d; }
  const float inv = rsqrtf(s2 * (1.f / kB) + kEPS);
  const float g = g1[j], bb = b1[j];
#pragma unroll
  for (int b = 0; b < kB; ++b) m1t[j * kB + b] = (v[b] - mean) * inv * g + bb;
}

// ---- 3a. split-K GEMM: part[kb][b][col] = sum_{k in kb} m1t[k][b]*w_go[k][col] ----
__global__ __launch_bounds__(256) void k_go_gemm2(const float* __restrict__ m1t,
                                                  const float* __restrict__ w_go,
                                                  float* __restrict__ part) {
  const int c0 = blockIdx.x * 1024 + threadIdx.x * 4;   // column base
  const int k0 = blockIdx.y * 128;                      // k-slice base
  float4 acc[kB];
#pragma unroll
  for (int b = 0; b < kB; ++b) acc[b] = make_float4(0.f, 0.f, 0.f, 0.f);
#pragma unroll 4
  for (int k = 0; k < 128; ++k) {
    const float4 w = *reinterpret_cast<const float4*>(&w_go[(size_t)(k0 + k) * 65536 + c0]);
    const float* mrow = m1t + (size_t)(k0 + k) * kB;   // uniform address -> s_load
#pragma unroll
    for (int b = 0; b < kB; ++b) {
      const float m = mrow[b];
      acc[b].x += m * w.x; acc[b].y += m * w.y;
      acc[b].z += m * w.z; acc[b].w += m * w.w;
    }
  }
  const size_t kb16 = (size_t)blockIdx.y * kB;
#pragma unroll
  for (int b = 0; b < kB; ++b) {
    *reinterpret_cast<float4*>(&part[(kb16 + b) * 65536 + c0]) = acc[b];
  }
}

// ---- 3b. reduce partials + bias + relu -> x[...,0:64] ----
__global__ __launch_bounds__(256) void k_go_reduce(const float* __restrict__ part,
                                                   const float* __restrict__ b_go,
                                                   float* __restrict__ x) {
  const int g = blockIdx.x * 256 + threadIdx.x;  // 0..262143 float4 ids
  const int b = g >> 14;                          // /16384
  const int cw = g & 16383;
  const int col = cw * 4;
  float4 a = *reinterpret_cast<const float4*>(&part[(size_t)b * 65536 + col]);
#pragma unroll
  for (int kb = 1; kb < 4; ++kb) {
    float4 p = *reinterpret_cast<const float4*>(&part[(size_t)(kb * kB + b) * 65536 + col]);
    a.x += p.x; a.y += p.y; a.z += p.z; a.w += p.w;
  }
  const float4 bg = *reinterpret_cast<const float4*>(&b_go[col]);
  a.x = fmaxf(a.x + bg.x, 0.f); a.y = fmaxf(a.y + bg.y, 0.f);
  a.z = fmaxf(a.z + bg.z, 0.f); a.w = fmaxf(a.w + bg.w, 0.f);
  const int n = col >> 6, c = col & 63;
  *reinterpret_cast<float4*>(&x[((size_t)(b * kN + n)) * kC + c]) = a;
}

// ---- 4. per-node BN over (b,c); fills nf half of x, normalizes in place ----
__global__ __launch_bounds__(256) void k_nf_bn(const float* __restrict__ nf,
                                               const float* __restrict__ g3,
                                               const float* __restrict__ b3,
                                               float* __restrict__ x) {
  const int n = blockIdx.x;
  const int tid = threadIdx.x;
  float s = 0.f, s2 = 0.f;
#pragma unroll
  for (int it = 0; it < 4; ++it) {
    int e = it * 256 + tid;
    int b = e >> 6, c = e & 63;
    float v = x[((size_t)(b * kN + n)) * kC + c];
    s += v; s2 += v * v;
  }
  if (tid < 64) {
    float v = nf[n * 64 + tid];
    s += 16.f * v; s2 += 16.f * v * v;
  }
  for (int o = 32; o > 0; o >>= 1) { s += __shfl_down(s, o); s2 += __shfl_down(s2, o); }
  __shared__ float ls[4], ls2[4];
  __shared__ float sscale, sshift;
  const int w = tid >> 6;
  if ((tid & 63) == 0) { ls[w] = s; ls2[w] = s2; }
  __syncthreads();
  if (tid == 0) {
    float S = ls[0] + ls[1] + ls[2] + ls[3];
    float S2 = ls2[0] + ls2[1] + ls2[2] + ls2[3];
    float mean = S * (1.f / 2048.f);
    float var = S2 * (1.f / 2048.f) - mean * mean;
    var = fmaxf(var, 0.f);
    float inv = rsqrtf(var + kEPS);
    float gg = g3[n];
    sscale = inv * gg;
    sshift = b3[n] - mean * inv * gg;
  }
  __syncthreads();
  const float scale = sscale, shift = sshift;
#pragma unroll
  for (int it = 0; it < 8; ++it) {
    int e = it * 256 + tid;
    int b = e >> 7, c = e & 127;
    size_t idx = ((size_t)(b * kN + n)) * kC + c;
    float v = (c < 64) ? x[idx] : nf[n * 64 + (c - 64)];
    x[idx] = v * scale + shift;
  }
}

// ---- 5. qk = x @ [wq|wk] : (16384,128)@(128,128) ----
__global__ __launch_bounds__(256) void k_qk(const float* __restrict__ x,
                                            const float* __restrict__ wq,
                                            const float* __restrict__ wk,
                                            float* __restrict__ qk) {
  __shared__ float a_s[32 * 68];
  __shared__ float w_s[32 * 128];
  const int row0 = blockIdx.x * 32;
  const int tid = threadIdx.x;
  const int tr = tid >> 5, tc = tid & 31;
  const int r0 = tr * 4, c0 = tc * 4;
  float acc[4][4] = {};
  for (int kc = 0; kc < 4; ++kc) {
    const int k0 = kc * 32;
    __syncthreads();
    {  // stage A: 32 rows x 32 k = 256 float4, one per thread
      int r = tid >> 3, kk4 = tid & 7;
      float4 v = *reinterpret_cast<const float4*>(&x[(size_t)(row0 + r) * kC + k0 + kk4 * 4]);
      *reinterpret_cast<float4*>(&a_s[r * 68 + kk4 * 4]) = v;
    }
    for (int it = 0; it < 16; ++it) {  // stage W: 32x128 scalars
      int e = it * 256 + tid;
      int kk = e >> 7, h2 = e & 127;
      int c = k0 + kk;
      float v = (h2 < 64) ? wq[c * 64 + h2] : wk[c * 64 + (h2 - 64)];
      w_s[kk * 128 + h2] = v;
    }
    __syncthreads();
#pragma unroll 8
    for (int k = 0; k < 32; ++k) {
      float a[4];
#pragma unroll
      for (int i = 0; i < 4; ++i) a[i] = a_s[(r0 + i) * 68 + k];
      float4 b4 = *reinterpret_cast<float4*>(&w_s[k * 128 + c0]);
      float bj[4] = {b4.x, b4.y, b4.z, b4.w};
#pragma unroll
      for (int i = 0; i < 4; ++i)
#pragma unroll
        for (int j = 0; j < 4; ++j) acc[i][j] += a[i] * bj[j];
    }
  }
#pragma unroll
  for (int i = 0; i < 4; ++i) {
    float4 o = {acc[i][0], acc[i][1], acc[i][2], acc[i][3]};
    *reinterpret_cast<float4*>(&qk[(size_t)(row0 + r0 + i) * kC + c0]) = o;
  }
}

// ---- 6. att[b,n,m] = q.k / 8 : 64x64 tiles ----
__global__ __launch_bounds__(256) void k_att(const float* __restrict__ qk,
                                             float* __restrict__ att) {
  const int mt = blockIdx.x, nt = blockIdx.y, b = blockIdx.z;
  __shared__ float qs[64 * 65], ks[64 * 65];
  const int tid = threadIdx.x;
  for (int it = 0; it < 16; ++it) {
    int e = it * 256 + tid;
    int r = e >> 6, h = e & 63;
    qs[r * 65 + h] = qk[(size_t)(b * kN + nt * 64 + r) * kC + h];
    ks[r * 65 + h] = qk[(size_t)(b * kN + mt * 64 + r) * kC + 64 + h];
  }
  __syncthreads();
  const int tr = tid >> 4, tc = tid & 15;
  const int r0 = tr * 4, c0 = tc * 4;
  float acc[4][4] = {};
#pragma unroll 8
  for (int k = 0; k < 64; ++k) {
    float a[4], bb[4];
#pragma unroll
    for (int i = 0; i < 4; ++i) a[i] = qs[(r0 + i) * 65 + k];
#pragma unroll
    for (int j = 0; j < 4; ++j) bb[j] = ks[(c0 + j) * 65 + k];
#pragma unroll
    for (int i = 0; i < 4; ++i)
#pragma unroll
      for (int j = 0; j < 4; ++j) acc[i][j] += a[i] * bb[j];
  }
  const float sc = 0.125f;  // 1/sqrt(64)
#pragma unroll
  for (int i = 0; i < 4; ++i) {
    float4 o = {acc[i][0] * sc, acc[i][1] * sc, acc[i][2] * sc, acc[i][3] * sc};
    *reinterpret_cast<float4*>(
        &att[(size_t)(b * kN + nt * 64 + r0 + i) * kN + mt * 64 + c0]) = o;
  }
}

// ---- 7a. column-softmax partial stats (online max/sum over n-chunks) ----
__global__ __launch_bounds__(256) void k_soft_stat(const float* __restrict__ att,
                                                   float* __restrict__ pmax,
                                                   float* __restrict__ psum) {
  const int b = blockIdx.x, ch = blockIdx.y;  // 16 x 16
  const int tid = threadIdx.x;
  const int m0 = tid * 4;
  float mx0 = -1e30f, mx1 = -1e30f, mx2 = -1e30f, mx3 = -1e30f;
  float sm0 = 0.f, sm1 = 0.f, sm2 = 0.f, sm3 = 0.f;
#pragma unroll 2
  for (int n = ch * 64; n < ch * 64 + 64; ++n) {
    float4 v = *reinterpret_cast<const float4*>(&att[(size_t)(b * kN + n) * kN + m0]);
    float nm;
    nm = fmaxf(mx0, v.x); sm0 = sm0 * __expf(mx0 - nm) + __expf(v.x - nm); mx0 = nm;
    nm = fmaxf(mx1, v.y); sm1 = sm1 * __expf(mx1 - nm) + __expf(v.y - nm); mx1 = nm;
    nm = fmaxf(mx2, v.z); sm2 = sm2 * __expf(mx2 - nm) + __expf(v.z - nm); mx2 = nm;
    nm = fmaxf(mx3, v.w); sm3 = sm3 * __expf(mx3 - nm) + __expf(v.w - nm); mx3 = nm;
  }
  const size_t base = (size_t)(b * 16 + ch) * kN + m0;
  float4 pm = {mx0, mx1, mx2, mx3};
  float4 ps = {sm0, sm1, sm2, sm3};
  *reinterpret_cast<float4*>(&pmax[base]) = pm;
  *reinterpret_cast<float4*>(&psum[base]) = ps;
}

// ---- 7b. combine chunk stats -> colmax, 1/colsum ----
__global__ __launch_bounds__(256) void k_soft_comb(const float* __restrict__ pmax,
                                                   const float* __restrict__ psum,
                                                   float* __restrict__ cmax,
                                                   float* __restrict__ cinv) {
  const int i = blockIdx.x * 256 + threadIdx.x;  // 16384
  const int b = i >> 10, m = i & 1023;
  float M = -1e30f;
#pragma unroll
  for (int c = 0; c < 16; ++c) M = fmaxf(M, pmax[(size_t)(b * 16 + c) * kN + m]);
  float S = 0.f;
#pragma unroll
  for (int c = 0; c < 16; ++c)
    S += psum[(size_t)(b * 16 + c) * kN + m] * __expf(pmax[(size_t)(b * 16 + c) * kN + m] - M);
  cmax[i] = M;
  cinv[i] = 1.f / S;
}

// ---- 7c-new. adj = go_adj + softmax -> bf16 hi/lo split ----
__global__ __launch_bounds__(256) void k_adj_split(const float* __restrict__ att,
                                                   const float* __restrict__ go_adj,
                                                   const float* __restrict__ cmax,
                                                   const float* __restrict__ cinv,
                                                   ushort* __restrict__ adj_hi,
                                                   ushort* __restrict__ adj_lo) {
  const size_t f4 = (size_t)blockIdx.x * 256 + threadIdx.x;  // 4,194,304
  const size_t e = f4 * 4;
  const int b = (int)(e >> 20);
  const int rem = (int)(e & 1048575);
  const int n = rem >> 10, m = rem & 1023;
  float4 v = *reinterpret_cast<const float4*>(&att[e]);
  float4 ga = *reinterpret_cast<const float4*>(&go_adj[n * kN + m]);
  float4 M = *reinterpret_cast<const float4*>(&cmax[b * kN + m]);
  float4 I = *reinterpret_cast<const float4*>(&cinv[b * kN + m]);
  float a0 = ga.x + __expf(v.x - M.x) * I.x;
  float a1 = ga.y + __expf(v.y - M.y) * I.y;
  float a2 = ga.z + __expf(v.z - M.z) * I.z;
  float a3 = ga.w + __expf(v.w - M.w) * I.w;
  ushort4 h, l;
  h.x = f2bf(a0); l.x = f2bf(a0 - bf2f(h.x));
  h.y = f2bf(a1); l.y = f2bf(a1 - bf2f(h.y));
  h.z = f2bf(a2); l.z = f2bf(a2 - bf2f(h.z));
  h.w = f2bf(a3); l.w = f2bf(a3 - bf2f(h.w));
  *reinterpret_cast<ushort4*>(&adj_hi[e]) = h;
  *reinterpret_cast<ushort4*>(&adj_lo[e]) = l;
}

// ---- 7c-old. adj = go_adj + softmax (in place on att), fp32 fallback ----
__global__ __launch_bounds__(256) void k_adj(float* __restrict__ att,
                                             const float* __restrict__ go_adj,
                                             const float* __restrict__ cmax,
                                             const float* __restrict__ cinv) {
  const size_t f4 = (size_t)blockIdx.x * 256 + threadIdx.x;
  const size_t e = f4 * 4;
  const int b = (int)(e >> 20);
  const int rem = (int)(e & 1048575);
  const int n = rem >> 10, m = rem & 1023;
  float4 v = *reinterpret_cast<float4*>(&att[e]);
  float4 ga = *reinterpret_cast<const float4*>(&go_adj[n * kN + m]);
  float4 M = *reinterpret_cast<const float4*>(&cmax[b * kN + m]);
  float4 I = *reinterpret_cast<const float4*>(&cinv[b * kN + m]);
  v.x = ga.x + __expf(v.x - M.x) * I.x;
  v.y = ga.y + __expf(v.y - M.y) * I.y;
  v.z = ga.z + __expf(v.z - M.z) * I.z;
  v.w = ga.w + __expf(v.w - M.w) * I.w;
  *reinterpret_cast<float4*>(&att[e]) = v;
}

// ---- T. transpose+split: src f32 [16][1024][128] -> xt_hi/lo bf16 [16][128][1024] ----
// block handles 64 n-rows x 128 c. Writes: lane = (c-group, n-chunk) so each
// wave emits 8 segments of 128 contiguous bytes per c-row (coalesced).
__global__ __launch_bounds__(256) void k_transp(const float* __restrict__ src,
                                                ushort* __restrict__ xt_hi,
                                                ushort* __restrict__ xt_lo) {
  const int nt = blockIdx.x, b = blockIdx.y;  // 16 x 16
  __shared__ float tile[64][133];
  const int tid = threadIdx.x;
#pragma unroll
  for (int it = 0; it < 8; ++it) {
    int e = it * 256 + tid;
    int r = e >> 5, c4 = e & 31;
    float4 v = *reinterpret_cast<const float4*>(&src[(size_t)(b * kN + nt * 64 + r) * kC + c4 * 4]);
    *reinterpret_cast<float4*>(&tile[r][c4 * 4]) = v;
  }
  __syncthreads();
  const int cl = tid >> 3;       // 0..31
  const int chunk = tid & 7;     // n chunk of 8
  const int n0 = chunk * 8;
#pragma unroll
  for (int cg = 0; cg < 4; ++cg) {
    const int c = cg * 32 + cl;
    const size_t obase = (size_t)(b * kC + c) * kN + nt * 64 + n0;
    ushort hs[8], ls[8];
#pragma unroll
    for (int j = 0; j < 8; ++j) {
      float v = tile[n0 + j][c];
      ushort h = f2bf(v);
      hs[j] = h;
      ls[j] = f2bf(v - bf2f(h));
    }
    *reinterpret_cast<uint4*>(&xt_hi[obase]) = *reinterpret_cast<uint4*>(hs);
    *reinterpret_cast<uint4*>(&xt_lo[obase]) = *reinterpret_cast<uint4*>(ls);
  }
}

// ---- 8-new. Y = alpha * adj @ X (- Zsub), LDS-staged bf16 split MFMA ----
// grid 256 (xcd-swizzled -> (b, rb)), block 512 = 8 waves.
// BM=64, BN=128, BK=64. Wave: rows [wr*16,+16), cols [wc*64,+64).
__global__ __launch_bounds__(512) void k_adjmm_mfma(const ushort* __restrict__ adj_hi,
                                                    const ushort* __restrict__ adj_lo,
                                                    const ushort* __restrict__ xt_hi,
                                                    const ushort* __restrict__ xt_lo,
                                                    const float* __restrict__ Zsub,
                                                    float* __restrict__ Y, float alpha) {
  const int bid = blockIdx.x;
  const int swz = (bid & 7) * 32 + (bid >> 3);  // bijective: 256 = 8*32
  const int b = swz >> 4, rb = swz & 15;
  __shared__ uint4 smem4[3072];  // 48 KiB
  char* smem = (char*)smem4;     // Ah@0 Al@8K Bh@16K Bl@32K
  const int tid = threadIdx.x;
  const int lane = tid & 63, w = tid >> 6;
  const int wr = w >> 1, wc = w & 1;
  const int l15 = lane & 15, lg = lane >> 4;

  f32x4 acc[4] = {{0.f, 0.f, 0.f, 0.f}, {0.f, 0.f, 0.f, 0.f},
                  {0.f, 0.f, 0.f, 0.f}, {0.f, 0.f, 0.f, 0.f}};
  const size_t adjrow0 = (size_t)b * kN + rb * 64;

  for (int kt = 0; kt < 16; ++kt) {
    const int k0 = kt * 64;
    __syncthreads();
    {  // stage A: 64 rows x 64 ushort (128B/row), 512 chunks of 16B -> 1 pass/buf
      const int r = tid >> 3, ch = tid & 7;
      const size_t g = (adjrow0 + r) * kN + k0 + ch * 8;
      const unsigned off = (unsigned)(r * 128 + ch * 16) ^ (unsigned)((r & 7) << 4);
      *reinterpret_cast<uint4*>(smem + off) = *reinterpret_cast<const uint4*>(adj_hi + g);
      *reinterpret_cast<uint4*>(smem + 8192 + off) = *reinterpret_cast<const uint4*>(adj_lo + g);
    }
#pragma unroll
    for (int p = 0; p < 2; ++p) {  // stage B: 128 c-rows x 64 ushort -> 2 passes/buf
      const int e = p * 512 + tid;
      const int c = e >> 3, ch = e & 7;
      const size_t g = ((size_t)b * kC + c) * kN + k0 + ch * 8;
      const unsigned off = (unsigned)(c * 128 + ch * 16) ^ (unsigned)((c & 7) << 4);
      *reinterpret_cast<uint4*>(smem + 16384 + off) = *reinterpret_cast<const uint4*>(xt_hi + g);
      *reinterpret_cast<uint4*>(smem + 32768 + off) = *reinterpret_cast<const uint4*>(xt_lo + g);
    }
    __syncthreads();
#pragma unroll
    for (int ss = 0; ss < 2; ++ss) {
      const int r = wr * 16 + l15;
      const unsigned aoff = (unsigned)(r * 128 + ss * 64 + lg * 16) ^ (unsigned)((r & 7) << 4);
      bfrag ah = *reinterpret_cast<const bfrag*>(smem + aoff);
      bfrag al = *reinterpret_cast<const bfrag*>(smem + 8192 + aoff);
      bfrag bh[4], bl[4];
#pragma unroll
      for (int ct = 0; ct < 4; ++ct) {
        const int c = wc * 64 + ct * 16 + l15;
        const unsigned boff = (unsigned)(c * 128 + ss * 64 + lg * 16) ^ (unsigned)((c & 7) << 4);
        bh[ct] = *reinterpret_cast<const bfrag*>(smem + 16384 + boff);
        bl[ct] = *reinterpret_cast<const bfrag*>(smem + 32768 + boff);
      }
#pragma unroll
      for (int ct = 0; ct < 4; ++ct) {
        acc[ct] = __builtin_amdgcn_mfma_f32_16x16x32_bf16(ah, bh[ct], acc[ct], 0, 0, 0);
        acc[ct] = __builtin_amdgcn_mfma_f32_16x16x32_bf16(ah, bl[ct], acc[ct], 0, 0, 0);
        acc[ct] = __builtin_amdgcn_mfma_f32_16x16x32_bf16(al, bh[ct], acc[ct], 0, 0, 0);
      }
    }
  }
  // epilogue: C/D layout col = lane&15, row = (lane>>4)*4 + i
  const int orow = rb * 64 + wr * 16 + lg * 4;
#pragma unroll
  for (int ct = 0; ct < 4; ++ct) {
    const int ocol = wc * 64 + ct * 16 + l15;
#pragma unroll
    for (int i = 0; i < 4; ++i) {
      const size_t idx = ((size_t)(b * kN + orow + i)) * kC + ocol;
      float v = alpha * acc[ct][i];
      if (Zsub) v -= Zsub[idx];
      Y[idx] = v;
    }
  }
}

// ---- 8-old. fp32 fallback adjmm ----
__global__ __launch_bounds__(256) void k_adjmm(const float* __restrict__ adj,
                                               const float* __restrict__ X,
                                               const float* __restrict__ Zsub,
                                               float* __restrict__ Y, float alpha) {
  const int nt = blockIdx.x, b = blockIdx.y;  // 32 x 16
  __shared__ float a_s[32 * 68];
  __shared__ float x_s[64 * 128];
  const int tid = threadIdx.x;
  const int tr = tid >> 5, tc = tid & 31;
  const int r0 = tr * 4, c0 = tc * 4;
  float acc[4][4] = {};
  const float* adjb = adj + (size_t)b * kN * kN;
  for (int kt = 0; kt < 16; ++kt) {
    const int k0 = kt * 64;
    __syncthreads();
#pragma unroll
    for (int it = 0; it < 2; ++it) {
      int e4 = it * 256 + tid;
      int r = e4 >> 4, kk4 = e4 & 15;
      float4 v = *reinterpret_cast<const float4*>(&adjb[(size_t)(nt * 32 + r) * kN + k0 + kk4 * 4]);
      *reinterpret_cast<float4*>(&a_s[r * 68 + kk4 * 4]) = v;
    }
#pragma unroll
    for (int it = 0; it < 8; ++it) {
      int e4 = it * 256 + tid;
      int k = e4 >> 5, c4 = e4 & 31;
      float4 v = *reinterpret_cast<const float4*>(&X[(size_t)(b * kN + k0 + k) * kC + c4 * 4]);
      *reinterpret_cast<float4*>(&x_s[k * 128 + c4 * 4]) = v;
    }
    __syncthreads();
#pragma unroll 8
    for (int k = 0; k < 64; ++k) {
      float a[4];
#pragma unroll
      for (int i = 0; i < 4; ++i) a[i] = a_s[(r0 + i) * 68 + k];
      float4 b4 = *reinterpret_cast<float4*>(&x_s[k * 128 + c0]);
      float bj[4] = {b4.x, b4.y, b4.z, b4.w};
#pragma unroll
      for (int i = 0; i < 4; ++i)
#pragma unroll
        for (int j = 0; j < 4; ++j) acc[i][j] += a[i] * bj[j];
    }
  }
#pragma unroll
  for (int i = 0; i < 4; ++i) {
    size_t idx = (size_t)(b * kN + nt * 32 + r0 + i) * kC + c0;
    float4 o = {alpha * acc[i][0], alpha * acc[i][1], alpha * acc[i][2], alpha * acc[i][3]};
    if (Zsub) {
      float4 z = *reinterpret_cast<const float4*>(&Zsub[idx]);
      o.x -= z.x; o.y -= z.y; o.z -= z.z; o.w -= z.w;
    }
    *reinterpret_cast<float4*>(&Y[idx]) = o;
  }
}

// ---- 9. z = x@th0 + tcur@th1 + tnext@th2 + x ----
__global__ __launch_bounds__(256) void k_theta(const float* __restrict__ x,
                                               const float* __restrict__ tcur,
                                               const float* __restrict__ tnext,
                                               const float* __restrict__ theta,
                                               float* __restrict__ z) {
  __shared__ float a_s[32 * 68];
  __shared__ float w_s[32 * 128];
  const int row0 = blockIdx.x * 32;
  const int tid = threadIdx.x;
  const int tr = tid >> 5, tc = tid & 31;
  const int r0 = tr * 4, c0 = tc * 4;
  float acc[4][4] = {};
  const float* srcs[3] = {x, tcur, tnext};
  for (int s = 0; s < 3; ++s) {
    const float* A = srcs[s];
    for (int kc = 0; kc < 4; ++kc) {
      const int k0 = kc * 32;
      __syncthreads();
      {
        int r = tid >> 3, kk4 = tid & 7;
        float4 v = *reinterpret_cast<const float4*>(&A[(size_t)(row0 + r) * kC + k0 + kk4 * 4]);
        *reinterpret_cast<float4*>(&a_s[r * 68 + kk4 * 4]) = v;
      }
#pragma unroll
      for (int it = 0; it < 4; ++it) {
        int e4 = it * 256 + tid;
        int kk = e4 >> 5, d4 = e4 & 31;
        float4 v = *reinterpret_cast<const float4*>(
            &theta[(size_t)s * 16384 + (size_t)(k0 + kk) * kC + d4 * 4]);
        *reinterpret_cast<float4*>(&w_s[kk * 128 + d4 * 4]) = v;
      }
      __syncthreads();
#pragma unroll 8
      for (int k = 0; k < 32; ++k) {
        float a[4];
#pragma unroll
        for (int i = 0; i < 4; ++i) a[i] = a_s[(r0 + i) * 68 + k];
        float4 b4 = *reinterpret_cast<float4*>(&w_s[k * 128 + c0]);
        float bj[4] = {b4.x, b4.y, b4.z, b4.w};
#pragma unroll
        for (int i = 0; i < 4; ++i)
#pragma unroll
          for (int j = 0; j < 4; ++j) acc[i][j] += a[i] * bj[j];
      }
    }
  }
#pragma unroll
  for (int i = 0; i < 4; ++i) {
    size_t idx = (size_t)(row0 + r0 + i) * kC + c0;
    float4 xv = *reinterpret_cast<const float4*>(&x[idx]);
    float4 o = {acc[i][0] + xv.x, acc[i][1] + xv.y, acc[i][2] + xv.z, acc[i][3] + xv.w};
    *reinterpret_cast<float4*>(&z[idx]) = o;
  }
}

// ---- 10. per-node BN + relu + dot(w_out) -> out (16,1024) ----
__global__ __launch_bounds__(256) void k_final(const float* __restrict__ z,
                                               const float* __restrict__ g4,
                                               const float* __restrict__ b4v,
                                               const float* __restrict__ w_out,
                                               const float* __restrict__ b_out,
                                               float* __restrict__ out) {
  const int n = blockIdx.x;
  const int tid = threadIdx.x;
  float s = 0.f, s2 = 0.f;
#pragma unroll
  for (int it = 0; it < 8; ++it) {
    int e = it * 256 + tid;
    int b = e >> 7, c = e & 127;
    float v = z[(size_t)(b * kN + n) * kC + c];
    s += v; s2 += v * v;
  }
  for (int o = 32; o > 0; o >>= 1) { s += __shfl_down(s, o); s2 += __shfl_down(s2, o); }
  __shared__ float ls[4], ls2[4];
  __shared__ float sscale, sshift;
  const int w = tid >> 6;
  if ((tid & 63) == 0) { ls[w] = s; ls2[w] = s2; }
  __syncthreads();
  if (tid == 0) {
    float S = ls[0] + ls[1] + ls[2] + ls[3];
    float S2 = ls2[0] + ls2[1] + ls2[2] + ls2[3];
    float mean = S * (1.f / 2048.f);
    float var = S2 * (1.f / 2048.f) - mean * mean;
    var = fmaxf(var, 0.f);
    float inv = rsqrtf(var + kEPS);
    float gg = g4[n];
    sscale = inv * gg;
    sshift = b4v[n] - mean * inv * gg;
  }
  __syncthreads();
  const float scale = sscale, shift = sshift;
  const int b = tid >> 4, c0 = (tid & 15) * 8;
  float p = 0.f;
#pragma unroll
  for (int j = 0; j < 8; ++j) {
    float v = z[(size_t)(b * kN + n) * kC + c0 + j] * scale + shift;
    v = fmaxf(v, 0.f);
    p += v * w_out[c0 + j];
  }
  for (int o = 8; o > 0; o >>= 1) p += __shfl_down(p, o, 16);
  if ((tid & 15) == 0) out[b * kN + n] = p + b_out[0];
}

extern "C" void kernel_launch(void* const* d_in, const int* in_sizes, int n_in,
                              void* d_out, int out_size, void* d_ws, size_t ws_size,
                              hipStream_t stream) {
  const int*   data = (const int*)d_in[0];
  const float* node_features = (const float*)d_in[1];
  const float* go_adj = (const float*)d_in[2];
  const float* emb  = (const float*)d_in[4];
  const float* w_go = (const float*)d_in[5];
  const float* b_go = (const float*)d_in[6];
  const float* wq   = (const float*)d_in[7];
  const float* wk   = (const float*)d_in[8];
  const float* theta= (const float*)d_in[9];
  const float* g1   = (const float*)d_in[10];
  const float* b1   = (const float*)d_in[11];
  const float* g3   = (const float*)d_in[12];
  const float* b3   = (const float*)d_in[13];
  const float* g4   = (const float*)d_in[14];
  const float* b4   = (const float*)d_in[15];
  const float* w_out= (const float*)d_in[16];
  const float* b_out= (const float*)d_in[17];

  float* ws = (float*)d_ws;
  float* featpart = ws + OFF_FEATPART;
  float* m1t   = ws + OFF_M1;
  float* x     = ws + OFF_X;
  float* qk    = ws + OFF_QK;   // reused as z later
  float* tcur  = ws + OFF_TCUR;
  float* tnext = ws + OFF_TNEXT;
  float* att   = ws + OFF_ATT;  // go-partials alias this region early
  float* pmax  = ws + OFF_PMAX;
  float* psum  = ws + OFF_PSUM;
  float* cmax  = ws + OFF_CMAX;
  float* cinv  = ws + OFF_CINV;
  ushort* adj_hi = (ushort*)(ws + OFF_ADJH);
  ushort* adj_lo = (ushort*)(ws + OFF_ADJL);
  ushort* xt_hi  = (ushort*)(ws + OFF_XTH);
  ushort* xt_lo  = (ushort*)(ws + OFF_XTL);

  const bool mfma_path = ws_size >= OFF_END * sizeof(float);

  k_embsum<<<dim3(16, 8), 256, 0, stream>>>(data, emb, featpart);
  k_bn_feat<<<1, 512, 0, stream>>>(featpart, data, g1, b1, m1t);
  k_go_gemm2<<<dim3(64, 4), 256, 0, stream>>>(m1t, w_go, att /* partials */);
  k_go_reduce<<<1024, 256, 0, stream>>>(att /* partials */, b_go, x);
  k_nf_bn<<<1024, 256, 0, stream>>>(node_features, g3, b3, x);
  k_qk<<<512, 256, 0, stream>>>(x, wq, wk, qk);
  k_att<<<dim3(16, 16, 16), 256, 0, stream>>>(qk, att);
  k_soft_stat<<<dim3(16, 16), 256, 0, stream>>>(att, pmax, psum);
  k_soft_comb<<<64, 256, 0, stream>>>(pmax, psum, cmax, cinv);
  if (mfma_path) {
    k_adj_split<<<16384, 256, 0, stream>>>(att, go_adj, cmax, cinv, adj_hi, adj_lo);
    k_transp<<<dim3(16, 16), 256, 0, stream>>>(x, xt_hi, xt_lo);
    k_adjmm_mfma<<<256, 512, 0, stream>>>(adj_hi, adj_lo, xt_hi, xt_lo,
                                          nullptr, tcur, 1.0f);
    k_transp<<<dim3(16, 16), 256, 0, stream>>>(tcur, xt_hi, xt_lo);
    k_adjmm_mfma<<<256, 512, 0, stream>>>(adj_hi, adj_lo, xt_hi, xt_lo,
                                          x, tnext, 2.0f);
  } else {
    k_adj<<<16384, 256, 0, stream>>>(att, go_adj, cmax, cinv);
    k_adjmm<<<dim3(32, 16), 256, 0, stream>>>(att, x, nullptr, tcur, 1.0f);
    k_adjmm<<<dim3(32, 16), 256, 0, stream>>>(att, tcur, x, tnext, 2.0f);
  }
  k_theta<<<512, 256, 0, stream>>>(x, tcur, tnext, theta, qk /* z */);
  k_final<<<1024, 256, 0, stream>>>(qk, g4, b4, w_out, b_out, (float*)d_out);
}

// Round 5
// 249.943 us; speedup vs baseline: 1.7049x; 1.2011x over previous
//
#include <hip/hip_runtime.h>

namespace {
constexpr int kB = 16;
constexpr int kMAXLEN = 1024;
constexpr int kPE = 256;
constexpr int kN = 1024;
constexpr int kEMB = 256;
constexpr int kC = 128;
constexpr float kEPS = 1e-5f;

// workspace offsets in floats
constexpr size_t OFF_FEATPART = 0;                       // 32768
constexpr size_t OFF_M1       = 32768;                   // m1t: 512*16
constexpr size_t OFF_X        = 65536;                   // 16*1024*128
constexpr size_t OFF_Z        = OFF_X   + 2097152;       // theta output
constexpr size_t OFF_TCUR     = OFF_Z   + 2097152;
constexpr size_t OFF_TNEXT    = OFF_TCUR+ 2097152;
constexpr size_t OFF_GOPART   = OFF_TNEXT+2097152;       // 4*16*65536 = 4194304
constexpr size_t OFF_PMAX     = OFF_GOPART + 4194304;    // 16*16*1024
constexpr size_t OFF_PSUM     = OFF_PMAX+ 262144;
constexpr size_t OFF_CMAX     = OFF_PSUM+ 262144;        // 16*1024
constexpr size_t OFF_CINV     = OFF_CMAX+ 16384;
// bf16 buffers (float units; each bf16 = 0.5 float)
constexpr size_t OFF_ADJH     = OFF_CINV + 16384;        // 16M bf16
constexpr size_t OFF_ADJL     = OFF_ADJH + 8388608;
constexpr size_t OFF_XTH      = OFF_ADJL + 8388608;      // 2M bf16 (x^T)
constexpr size_t OFF_XTL      = OFF_XTH  + 1048576;
constexpr size_t OFF_QH       = OFF_XTL  + 1048576;      // 16384*64 bf16
constexpr size_t OFF_QL       = OFF_QH   + 524288;
constexpr size_t OFF_KH       = OFF_QL   + 524288;
constexpr size_t OFF_KL       = OFF_KH   + 524288;

typedef __attribute__((ext_vector_type(8))) short bfrag;
typedef __attribute__((ext_vector_type(4))) float f32x4;

__device__ inline ushort f2bf(float f) {
  unsigned u = __float_as_uint(f);
  unsigned r = (u + 0x7FFFu + ((u >> 16) & 1u)) >> 16;  // RNE
  return (ushort)r;
}
__device__ inline float bf2f(ushort h) { return __uint_as_float(((unsigned)h) << 16); }
} // namespace

// ---- 1. embedding gather partial sums ----
__global__ __launch_bounds__(256) void k_embsum(const int* __restrict__ data,
                                                const float* __restrict__ emb,
                                                float* __restrict__ featpart) {
  const int b = blockIdx.x, ch = blockIdx.y;   // 16 x 8
  const int e = threadIdx.x;                   // 256
  const int* row = data + b * (kMAXLEN + kPE) + ch * 128;
  float acc = 0.f;
#pragma unroll 4
  for (int l = 0; l < 128; ++l) {
    acc += emb[(size_t)row[l] * kEMB + e];
  }
  featpart[((b * 8 + ch) << 8) + e] = acc;
}

// ---- 2. BN over batch -> m1t (512,16) transposed ----
__global__ __launch_bounds__(512) void k_bn_feat(const float* __restrict__ featpart,
                                                 const int* __restrict__ data,
                                                 const float* __restrict__ g1,
                                                 const float* __restrict__ b1,
                                                 float* __restrict__ m1t) {
  const int j = threadIdx.x;
  float v[kB];
  if (j < kPE) {
    const float pe = sinf((float)j);
#pragma unroll
    for (int b = 0; b < kB; ++b) {
      float s = 0.f;
      for (int ch = 0; ch < 8; ++ch) s += featpart[((b * 8 + ch) << 8) + j];
      v[b] = s * (1.f / 1024.f) + pe;
    }
  } else {
    const int e = j - kPE;
    const float pe = sinf((float)e);
#pragma unroll
    for (int b = 0; b < kB; ++b)
      v[b] = (float)data[b * (kMAXLEN + kPE) + kMAXLEN + e] + pe;
  }
  float s = 0.f;
#pragma unroll
  for (int b = 0; b < kB; ++b) s += v[b];
  const float mean = s * (1.f / kB);
  float s2 = 0.f;
#pragma unroll
  for (int b = 0; b < kB; ++b) { float d = v[b] - mean; s2 += d * d; }
  const float inv = rsqrtf(s2 * (1.f / kB) + kEPS);
  const float g = g1[j], bb = b1[j];
#pragma unroll
  for (int b = 0; b < kB; ++b) m1t[j * kB + b] = (v[b] - mean) * inv * g + bb;
}

// ---- 3a. split-K GEMM (m1t via SGPR broadcast) ----
__global__ __launch_bounds__(256) void k_go_gemm2(const float* __restrict__ m1t,
                                                  const float* __restrict__ w_go,
                                                  float* __restrict__ part) {
  const int c0 = blockIdx.x * 1024 + threadIdx.x * 4;
  const int k0 = blockIdx.y * 128;
  float4 acc[kB];
#pragma unroll
  for (int b = 0; b < kB; ++b) acc[b] = make_float4(0.f, 0.f, 0.f, 0.f);
#pragma unroll 4
  for (int k = 0; k < 128; ++k) {
    const float4 w = *reinterpret_cast<const float4*>(&w_go[(size_t)(k0 + k) * 65536 + c0]);
    const float* mrow = m1t + (size_t)(k0 + k) * kB;
#pragma unroll
    for (int b = 0; b < kB; ++b) {
      const float m = mrow[b];
      acc[b].x += m * w.x; acc[b].y += m * w.y;
      acc[b].z += m * w.z; acc[b].w += m * w.w;
    }
  }
  const size_t kb16 = (size_t)blockIdx.y * kB;
#pragma unroll
  for (int b = 0; b < kB; ++b) {
    *reinterpret_cast<float4*>(&part[(kb16 + b) * 65536 + c0]) = acc[b];
  }
}

// ---- 3b. reduce partials + bias + relu -> x[...,0:64] ----
__global__ __launch_bounds__(256) void k_go_reduce(const float* __restrict__ part,
                                                   const float* __restrict__ b_go,
                                                   float* __restrict__ x) {
  const int g = blockIdx.x * 256 + threadIdx.x;
  const int b = g >> 14;
  const int cw = g & 16383;
  const int col = cw * 4;
  float4 a = *reinterpret_cast<const float4*>(&part[(size_t)b * 65536 + col]);
#pragma unroll
  for (int kb = 1; kb < 4; ++kb) {
    float4 p = *reinterpret_cast<const float4*>(&part[(size_t)(kb * kB + b) * 65536 + col]);
    a.x += p.x; a.y += p.y; a.z += p.z; a.w += p.w;
  }
  const float4 bg = *reinterpret_cast<const float4*>(&b_go[col]);
  a.x = fmaxf(a.x + bg.x, 0.f); a.y = fmaxf(a.y + bg.y, 0.f);
  a.z = fmaxf(a.z + bg.z, 0.f); a.w = fmaxf(a.w + bg.w, 0.f);
  const int n = col >> 6, c = col & 63;
  *reinterpret_cast<float4*>(&x[((size_t)(b * kN + n)) * kC + c]) = a;
}

// ---- 4. per-node BN over (b,c) ----
__global__ __launch_bounds__(256) void k_nf_bn(const float* __restrict__ nf,
                                               const float* __restrict__ g3,
                                               const float* __restrict__ b3,
                                               float* __restrict__ x) {
  const int n = blockIdx.x;
  const int tid = threadIdx.x;
  float s = 0.f, s2 = 0.f;
#pragma unroll
  for (int it = 0; it < 4; ++it) {
    int e = it * 256 + tid;
    int b = e >> 6, c = e & 63;
    float v = x[((size_t)(b * kN + n)) * kC + c];
    s += v; s2 += v * v;
  }
  if (tid < 64) {
    float v = nf[n * 64 + tid];
    s += 16.f * v; s2 += 16.f * v * v;
  }
  for (int o = 32; o > 0; o >>= 1) { s += __shfl_down(s, o); s2 += __shfl_down(s2, o); }
  __shared__ float ls[4], ls2[4];
  __shared__ float sscale, sshift;
  const int w = tid >> 6;
  if ((tid & 63) == 0) { ls[w] = s; ls2[w] = s2; }
  __syncthreads();
  if (tid == 0) {
    float S = ls[0] + ls[1] + ls[2] + ls[3];
    float S2 = ls2[0] + ls2[1] + ls2[2] + ls2[3];
    float mean = S * (1.f / 2048.f);
    float var = S2 * (1.f / 2048.f) - mean * mean;
    var = fmaxf(var, 0.f);
    float inv = rsqrtf(var + kEPS);
    float gg = g3[n];
    sscale = inv * gg;
    sshift = b3[n] - mean * inv * gg;
  }
  __syncthreads();
  const float scale = sscale, shift = sshift;
#pragma unroll
  for (int it = 0; it < 8; ++it) {
    int e = it * 256 + tid;
    int b = e >> 7, c = e & 127;
    size_t idx = ((size_t)(b * kN + n)) * kC + c;
    float v = (c < 64) ? x[idx] : nf[n * 64 + (c - 64)];
    x[idx] = v * scale + shift;
  }
}

// ---- 5. q/k projections -> bf16 hi/lo, [bn][64] layout ----
__global__ __launch_bounds__(256) void k_qkgen(const float* __restrict__ x,
                                               const float* __restrict__ wq,
                                               const float* __restrict__ wk,
                                               ushort* __restrict__ qh, ushort* __restrict__ ql,
                                               ushort* __restrict__ kh, ushort* __restrict__ kl) {
  __shared__ float a_s[32 * 68];
  __shared__ float w_s[32 * 128];
  const int row0 = blockIdx.x * 32;
  const int tid = threadIdx.x;
  const int tr = tid >> 5, tc = tid & 31;
  const int r0 = tr * 4, c0 = tc * 4;
  float acc[4][4] = {};
  for (int kc = 0; kc < 4; ++kc) {
    const int k0 = kc * 32;
    __syncthreads();
    {
      int r = tid >> 3, kk4 = tid & 7;
      float4 v = *reinterpret_cast<const float4*>(&x[(size_t)(row0 + r) * kC + k0 + kk4 * 4]);
      *reinterpret_cast<float4*>(&a_s[r * 68 + kk4 * 4]) = v;
    }
    for (int it = 0; it < 16; ++it) {
      int e = it * 256 + tid;
      int kk = e >> 7, h2 = e & 127;
      int c = k0 + kk;
      float v = (h2 < 64) ? wq[c * 64 + h2] : wk[c * 64 + (h2 - 64)];
      w_s[kk * 128 + h2] = v;
    }
    __syncthreads();
#pragma unroll 8
    for (int k = 0; k < 32; ++k) {
      float a[4];
#pragma unroll
      for (int i = 0; i < 4; ++i) a[i] = a_s[(r0 + i) * 68 + k];
      float4 b4 = *reinterpret_cast<float4*>(&w_s[k * 128 + c0]);
      float bj[4] = {b4.x, b4.y, b4.z, b4.w};
#pragma unroll
      for (int i = 0; i < 4; ++i)
#pragma unroll
        for (int j = 0; j < 4; ++j) acc[i][j] += a[i] * bj[j];
    }
  }
  const bool isq = (c0 < 64);
  const int h0 = isq ? c0 : (c0 - 64);
  ushort* oh = isq ? qh : kh;
  ushort* ol = isq ? ql : kl;
#pragma unroll
  for (int i = 0; i < 4; ++i) {
    ushort hs[4], ls[4];
#pragma unroll
    for (int j = 0; j < 4; ++j) {
      float v = acc[i][j];
      ushort h = f2bf(v);
      hs[j] = h;
      ls[j] = f2bf(v - bf2f(h));
    }
    const size_t o = (size_t)(row0 + r0 + i) * 64 + h0;
    *reinterpret_cast<ushort4*>(&oh[o]) = *reinterpret_cast<ushort4*>(hs);
    *reinterpret_cast<ushort4*>(&ol[o]) = *reinterpret_cast<ushort4*>(ls);
  }
}

// ---- 6. att stats via MFMA: C[m][n] = K·Q^T, per-(b,nt) partial max/sum over n ----
// grid (16 nt, 16 b), 512 thr = 8 waves. K tile 128m x 64h per chunk, Q tile 64n x 64h.
__global__ __launch_bounds__(512) void k_att_stats(const ushort* __restrict__ qh,
                                                   const ushort* __restrict__ ql,
                                                   const ushort* __restrict__ kh,
                                                   const ushort* __restrict__ kl,
                                                   float* __restrict__ pmax,
                                                   float* __restrict__ psum) {
  const int nt = blockIdx.x, b = blockIdx.y;
  __shared__ uint4 smem4[3072];  // 48 KiB: Qh@0 Ql@8K Kh@16K Kl@32K
  char* smem = (char*)smem4;
  const int tid = threadIdx.x;
  const int lane = tid & 63, w = tid >> 6;
  const int l15 = lane & 15, lg = lane >> 4;

  {  // stage Q once: 64 rows x 64 h
    const int r = tid >> 3, ch = tid & 7;
    const size_t g = (size_t)(b * kN + nt * 64 + r) * 64 + ch * 8;
    const unsigned off = (unsigned)(r * 128 + ch * 16) ^ (unsigned)((r & 7) << 4);
    *reinterpret_cast<uint4*>(smem + off) = *reinterpret_cast<const uint4*>(qh + g);
    *reinterpret_cast<uint4*>(smem + 8192 + off) = *reinterpret_cast<const uint4*>(ql + g);
  }

  for (int mc = 0; mc < 8; ++mc) {
    __syncthreads();
#pragma unroll
    for (int p = 0; p < 2; ++p) {  // stage K chunk: 128 m-rows x 64 h
      const int e = p * 512 + tid;
      const int c = e >> 3, ch = e & 7;
      const size_t g = (size_t)(b * kN + mc * 128 + c) * 64 + ch * 8;
      const unsigned off = (unsigned)(c * 128 + ch * 16) ^ (unsigned)((c & 7) << 4);
      *reinterpret_cast<uint4*>(smem + 16384 + off) = *reinterpret_cast<const uint4*>(kh + g);
      *reinterpret_cast<uint4*>(smem + 32768 + off) = *reinterpret_cast<const uint4*>(kl + g);
    }
    __syncthreads();
    f32x4 acc[4] = {{0.f,0.f,0.f,0.f},{0.f,0.f,0.f,0.f},{0.f,0.f,0.f,0.f},{0.f,0.f,0.f,0.f}};
#pragma unroll
    for (int ss = 0; ss < 2; ++ss) {
      const int r = w * 16 + l15;  // m-row within chunk
      const unsigned aoff = (unsigned)(r * 128 + ss * 64 + lg * 16) ^ (unsigned)((r & 7) << 4);
      bfrag ah = *reinterpret_cast<const bfrag*>(smem + 16384 + aoff);
      bfrag al = *reinterpret_cast<const bfrag*>(smem + 32768 + aoff);
#pragma unroll
      for (int nf = 0; nf < 4; ++nf) {
        const int c = nf * 16 + l15;  // n-col
        const unsigned boff = (unsigned)(c * 128 + ss * 64 + lg * 16) ^ (unsigned)((c & 7) << 4);
        bfrag bh = *reinterpret_cast<const bfrag*>(smem + boff);
        bfrag bl = *reinterpret_cast<const bfrag*>(smem + 8192 + boff);
        acc[nf] = __builtin_amdgcn_mfma_f32_16x16x32_bf16(ah, bh, acc[nf], 0, 0, 0);
        acc[nf] = __builtin_amdgcn_mfma_f32_16x16x32_bf16(ah, bl, acc[nf], 0, 0, 0);
        acc[nf] = __builtin_amdgcn_mfma_f32_16x16x32_bf16(al, bh, acc[nf], 0, 0, 0);
      }
    }
    // stats over n (64 values per m-row): cols live in lane&15 across 4 frags
#pragma unroll
    for (int i = 0; i < 4; ++i) {
      float v0 = acc[0][i] * 0.125f, v1 = acc[1][i] * 0.125f;
      float v2 = acc[2][i] * 0.125f, v3 = acc[3][i] * 0.125f;
      float mx = fmaxf(fmaxf(v0, v1), fmaxf(v2, v3));
#pragma unroll
      for (int msk = 1; msk < 16; msk <<= 1) mx = fmaxf(mx, __shfl_xor(mx, msk));
      float sm = __expf(v0 - mx) + __expf(v1 - mx) + __expf(v2 - mx) + __expf(v3 - mx);
#pragma unroll
      for (int msk = 1; msk < 16; msk <<= 1) sm += __shfl_xor(sm, msk);
      if (l15 == 0) {
        const int m = mc * 128 + w * 16 + lg * 4 + i;
        const size_t o = (size_t)(b * 16 + nt) * kN + m;
        pmax[o] = mx;
        psum[o] = sm;
      }
    }
  }
}

// ---- 7. combine chunk stats -> colmax, 1/colsum ----
__global__ __launch_bounds__(256) void k_soft_comb(const float* __restrict__ pmax,
                                                   const float* __restrict__ psum,
                                                   float* __restrict__ cmax,
                                                   float* __restrict__ cinv) {
  const int i = blockIdx.x * 256 + threadIdx.x;
  const int b = i >> 10, m = i & 1023;
  float M = -1e30f;
#pragma unroll
  for (int c = 0; c < 16; ++c) M = fmaxf(M, pmax[(size_t)(b * 16 + c) * kN + m]);
  float S = 0.f;
#pragma unroll
  for (int c = 0; c < 16; ++c)
    S += psum[(size_t)(b * 16 + c) * kN + m] * __expf(pmax[(size_t)(b * 16 + c) * kN + m] - M);
  cmax[i] = M;
  cinv[i] = 1.f / S;
}

// ---- 8. adj emit: recompute Q·K^T, adj = go_adj + exp(.-M)*I -> bf16 hi/lo ----
// grid (8 mc, 16 nt, 16 b), 512 thr = 8 waves. Wave: 32n x 32m (2x2 frags).
__global__ __launch_bounds__(512) void k_adj_emit(const ushort* __restrict__ qh,
                                                  const ushort* __restrict__ ql,
                                                  const ushort* __restrict__ kh,
                                                  const ushort* __restrict__ kl,
                                                  const float* __restrict__ go_adj,
                                                  const float* __restrict__ cmax,
                                                  const float* __restrict__ cinv,
                                                  ushort* __restrict__ adj_hi,
                                                  ushort* __restrict__ adj_lo) {
  const int mc = blockIdx.x, nt = blockIdx.y, b = blockIdx.z;
  __shared__ uint4 smem4[3072];  // 48 KiB: Qh@0 Ql@8K Kh@16K Kl@32K ; C32 overlay @0
  char* smem = (char*)smem4;
  float* c32 = (float*)smem4;    // [64][132] after MFMA
  const int tid = threadIdx.x;
  const int lane = tid & 63, w = tid >> 6;
  const int wr = w >> 2, wc = w & 3;
  const int l15 = lane & 15, lg = lane >> 4;

  {  // stage Q: 64 n-rows x 64 h
    const int r = tid >> 3, ch = tid & 7;
    const size_t g = (size_t)(b * kN + nt * 64 + r) * 64 + ch * 8;
    const unsigned off = (unsigned)(r * 128 + ch * 16) ^ (unsigned)((r & 7) << 4);
    *reinterpret_cast<uint4*>(smem + off) = *reinterpret_cast<const uint4*>(qh + g);
    *reinterpret_cast<uint4*>(smem + 8192 + off) = *reinterpret_cast<const uint4*>(ql + g);
  }
#pragma unroll
  for (int p = 0; p < 2; ++p) {  // stage K: 128 m-rows x 64 h
    const int e = p * 512 + tid;
    const int c = e >> 3, ch = e & 7;
    const size_t g = (size_t)(b * kN + mc * 128 + c) * 64 + ch * 8;
    const unsigned off = (unsigned)(c * 128 + ch * 16) ^ (unsigned)((c & 7) << 4);
    *reinterpret_cast<uint4*>(smem + 16384 + off) = *reinterpret_cast<const uint4*>(kh + g);
    *reinterpret_cast<uint4*>(smem + 32768 + off) = *reinterpret_cast<const uint4*>(kl + g);
  }
  __syncthreads();
  f32x4 acc[2][2] = {{{0.f,0.f,0.f,0.f},{0.f,0.f,0.f,0.f}},
                     {{0.f,0.f,0.f,0.f},{0.f,0.f,0.f,0.f}}};
#pragma unroll
  for (int ss = 0; ss < 2; ++ss) {
    bfrag ah[2], al[2], bh[2], bl[2];
#pragma unroll
    for (int nf = 0; nf < 2; ++nf) {
      const int r = wr * 32 + nf * 16 + l15;   // n row
      const unsigned aoff = (unsigned)(r * 128 + ss * 64 + lg * 16) ^ (unsigned)((r & 7) << 4);
      ah[nf] = *reinterpret_cast<const bfrag*>(smem + aoff);
      al[nf] = *reinterpret_cast<const bfrag*>(smem + 8192 + aoff);
    }
#pragma unroll
    for (int mf = 0; mf < 2; ++mf) {
      const int c = wc * 32 + mf * 16 + l15;   // m col
      const unsigned boff = (unsigned)(c * 128 + ss * 64 + lg * 16) ^ (unsigned)((c & 7) << 4);
      bh[mf] = *reinterpret_cast<const bfrag*>(smem + 16384 + boff);
      bl[mf] = *reinterpret_cast<const bfrag*>(smem + 32768 + boff);
    }
#pragma unroll
    for (int nf = 0; nf < 2; ++nf)
#pragma unroll
      for (int mf = 0; mf < 2; ++mf) {
        acc[nf][mf] = __builtin_amdgcn_mfma_f32_16x16x32_bf16(ah[nf], bh[mf], acc[nf][mf], 0, 0, 0);
        acc[nf][mf] = __builtin_amdgcn_mfma_f32_16x16x32_bf16(ah[nf], bl[mf], acc[nf][mf], 0, 0, 0);
        acc[nf][mf] = __builtin_amdgcn_mfma_f32_16x16x32_bf16(al[nf], bh[mf], acc[nf][mf], 0, 0, 0);
      }
  }
  __syncthreads();  // all LDS reads done; overlay C32
#pragma unroll
  for (int mf = 0; mf < 2; ++mf) {
    const int mLoc = wc * 32 + mf * 16 + l15;
    const int mG = b * kN + mc * 128 + mLoc;
    const float M = cmax[mG], I = cinv[mG];
#pragma unroll
    for (int nf = 0; nf < 2; ++nf) {
#pragma unroll
      for (int i = 0; i < 4; ++i) {
        const int nLoc = wr * 32 + nf * 16 + lg * 4 + i;
        c32[nLoc * 132 + mLoc] = __expf(acc[nf][mf][i] * 0.125f - M) * I;
      }
    }
  }
  __syncthreads();
#pragma unroll
  for (int p = 0; p < 2; ++p) {  // coalesced emit: 64 rows x 128 m in 8-elem chunks
    const int e = p * 512 + tid;
    const int n = e >> 4, m0 = (e & 15) * 8;
    const float* cr = &c32[n * 132 + m0];
    const float* ga = &go_adj[(size_t)(nt * 64 + n) * kN + mc * 128 + m0];
    ushort hs[8], ls[8];
#pragma unroll
    for (int j = 0; j < 8; ++j) {
      float v = cr[j] + ga[j];
      ushort h = f2bf(v);
      hs[j] = h;
      ls[j] = f2bf(v - bf2f(h));
    }
    const size_t o = (size_t)(b * kN + nt * 64 + n) * kN + mc * 128 + m0;
    *reinterpret_cast<uint4*>(&adj_hi[o]) = *reinterpret_cast<uint4*>(hs);
    *reinterpret_cast<uint4*>(&adj_lo[o]) = *reinterpret_cast<uint4*>(ls);
  }
}

// ---- T. transpose+split: f32 [16][1024][128] -> bf16 hi/lo [16][128][1024] ----
__global__ __launch_bounds__(256) void k_transp(const float* __restrict__ src,
                                                ushort* __restrict__ xt_hi,
                                                ushort* __restrict__ xt_lo) {
  const int nt = blockIdx.x, b = blockIdx.y;
  __shared__ float tile[64][133];
  const int tid = threadIdx.x;
#pragma unroll
  for (int it = 0; it < 8; ++it) {
    int e = it * 256 + tid;
    int r = e >> 5, c4 = e & 31;
    float4 v = *reinterpret_cast<const float4*>(&src[(size_t)(b * kN + nt * 64 + r) * kC + c4 * 4]);
    *reinterpret_cast<float4*>(&tile[r][c4 * 4]) = v;
  }
  __syncthreads();
  const int cl = tid >> 3;
  const int chunk = tid & 7;
  const int n0 = chunk * 8;
#pragma unroll
  for (int cg = 0; cg < 4; ++cg) {
    const int c = cg * 32 + cl;
    const size_t obase = (size_t)(b * kC + c) * kN + nt * 64 + n0;
    ushort hs[8], ls[8];
#pragma unroll
    for (int j = 0; j < 8; ++j) {
      float v = tile[n0 + j][c];
      ushort h = f2bf(v);
      hs[j] = h;
      ls[j] = f2bf(v - bf2f(h));
    }
    *reinterpret_cast<uint4*>(&xt_hi[obase]) = *reinterpret_cast<uint4*>(hs);
    *reinterpret_cast<uint4*>(&xt_lo[obase]) = *reinterpret_cast<uint4*>(ls);
  }
}

// ---- 9. Y = alpha * adj @ X (- Zsub), LDS-staged bf16 split MFMA ----
__global__ __launch_bounds__(512) void k_adjmm_mfma(const ushort* __restrict__ adj_hi,
                                                    const ushort* __restrict__ adj_lo,
                                                    const ushort* __restrict__ xt_hi,
                                                    const ushort* __restrict__ xt_lo,
                                                    const float* __restrict__ Zsub,
                                                    float* __restrict__ Y, float alpha) {
  const int bid = blockIdx.x;
  const int swz = (bid & 7) * 32 + (bid >> 3);
  const int b = swz >> 4, rb = swz & 15;
  __shared__ uint4 smem4[3072];
  char* smem = (char*)smem4;
  const int tid = threadIdx.x;
  const int lane = tid & 63, w = tid >> 6;
  const int wr = w >> 1, wc = w & 1;
  const int l15 = lane & 15, lg = lane >> 4;

  f32x4 acc[4] = {{0.f,0.f,0.f,0.f},{0.f,0.f,0.f,0.f},{0.f,0.f,0.f,0.f},{0.f,0.f,0.f,0.f}};
  const size_t adjrow0 = (size_t)b * kN + rb * 64;

  for (int kt = 0; kt < 16; ++kt) {
    const int k0 = kt * 64;
    __syncthreads();
    {
      const int r = tid >> 3, ch = tid & 7;
      const size_t g = (adjrow0 + r) * kN + k0 + ch * 8;
      const unsigned off = (unsigned)(r * 128 + ch * 16) ^ (unsigned)((r & 7) << 4);
      *reinterpret_cast<uint4*>(smem + off) = *reinterpret_cast<const uint4*>(adj_hi + g);
      *reinterpret_cast<uint4*>(smem + 8192 + off) = *reinterpret_cast<const uint4*>(adj_lo + g);
    }
#pragma unroll
    for (int p = 0; p < 2; ++p) {
      const int e = p * 512 + tid;
      const int c = e >> 3, ch = e & 7;
      const size_t g = ((size_t)b * kC + c) * kN + k0 + ch * 8;
      const unsigned off = (unsigned)(c * 128 + ch * 16) ^ (unsigned)((c & 7) << 4);
      *reinterpret_cast<uint4*>(smem + 16384 + off) = *reinterpret_cast<const uint4*>(xt_hi + g);
      *reinterpret_cast<uint4*>(smem + 32768 + off) = *reinterpret_cast<const uint4*>(xt_lo + g);
    }
    __syncthreads();
#pragma unroll
    for (int ss = 0; ss < 2; ++ss) {
      const int r = wr * 16 + l15;
      const unsigned aoff = (unsigned)(r * 128 + ss * 64 + lg * 16) ^ (unsigned)((r & 7) << 4);
      bfrag ah = *reinterpret_cast<const bfrag*>(smem + aoff);
      bfrag al = *reinterpret_cast<const bfrag*>(smem + 8192 + aoff);
      bfrag bh[4], bl[4];
#pragma unroll
      for (int ct = 0; ct < 4; ++ct) {
        const int c = wc * 64 + ct * 16 + l15;
        const unsigned boff = (unsigned)(c * 128 + ss * 64 + lg * 16) ^ (unsigned)((c & 7) << 4);
        bh[ct] = *reinterpret_cast<const bfrag*>(smem + 16384 + boff);
        bl[ct] = *reinterpret_cast<const bfrag*>(smem + 32768 + boff);
      }
#pragma unroll
      for (int ct = 0; ct < 4; ++ct) {
        acc[ct] = __builtin_amdgcn_mfma_f32_16x16x32_bf16(ah, bh[ct], acc[ct], 0, 0, 0);
        acc[ct] = __builtin_amdgcn_mfma_f32_16x16x32_bf16(ah, bl[ct], acc[ct], 0, 0, 0);
        acc[ct] = __builtin_amdgcn_mfma_f32_16x16x32_bf16(al, bh[ct], acc[ct], 0, 0, 0);
      }
    }
  }
  const int orow = rb * 64 + wr * 16 + lg * 4;
#pragma unroll
  for (int ct = 0; ct < 4; ++ct) {
    const int ocol = wc * 64 + ct * 16 + l15;
#pragma unroll
    for (int i = 0; i < 4; ++i) {
      const size_t idx = ((size_t)(b * kN + orow + i)) * kC + ocol;
      float v = alpha * acc[ct][i];
      if (Zsub) v -= Zsub[idx];
      Y[idx] = v;
    }
  }
}

// ---- 10. z = x@th0 + tcur@th1 + tnext@th2 + x ----
__global__ __launch_bounds__(256) void k_theta(const float* __restrict__ x,
                                               const float* __restrict__ tcur,
                                               const float* __restrict__ tnext,
                                               const float* __restrict__ theta,
                                               float* __restrict__ z) {
  __shared__ float a_s[32 * 68];
  __shared__ float w_s[32 * 128];
  const int row0 = blockIdx.x * 32;
  const int tid = threadIdx.x;
  const int tr = tid >> 5, tc = tid & 31;
  const int r0 = tr * 4, c0 = tc * 4;
  float acc[4][4] = {};
  const float* srcs[3] = {x, tcur, tnext};
  for (int s = 0; s < 3; ++s) {
    const float* A = srcs[s];
    for (int kc = 0; kc < 4; ++kc) {
      const int k0 = kc * 32;
      __syncthreads();
      {
        int r = tid >> 3, kk4 = tid & 7;
        float4 v = *reinterpret_cast<const float4*>(&A[(size_t)(row0 + r) * kC + k0 + kk4 * 4]);
        *reinterpret_cast<float4*>(&a_s[r * 68 + kk4 * 4]) = v;
      }
#pragma unroll
      for (int it = 0; it < 4; ++it) {
        int e4 = it * 256 + tid;
        int kk = e4 >> 5, d4 = e4 & 31;
        float4 v = *reinterpret_cast<const float4*>(
            &theta[(size_t)s * 16384 + (size_t)(k0 + kk) * kC + d4 * 4]);
        *reinterpret_cast<float4*>(&w_s[kk * 128 + d4 * 4]) = v;
      }
      __syncthreads();
#pragma unroll 8
      for (int k = 0; k < 32; ++k) {
        float a[4];
#pragma unroll
        for (int i = 0; i < 4; ++i) a[i] = a_s[(r0 + i) * 68 + k];
        float4 b4 = *reinterpret_cast<float4*>(&w_s[k * 128 + c0]);
        float bj[4] = {b4.x, b4.y, b4.z, b4.w};
#pragma unroll
        for (int i = 0; i < 4; ++i)
#pragma unroll
          for (int j = 0; j < 4; ++j) acc[i][j] += a[i] * bj[j];
      }
    }
  }
#pragma unroll
  for (int i = 0; i < 4; ++i) {
    size_t idx = (size_t)(row0 + r0 + i) * kC + c0;
    float4 xv = *reinterpret_cast<const float4*>(&x[idx]);
    float4 o = {acc[i][0] + xv.x, acc[i][1] + xv.y, acc[i][2] + xv.z, acc[i][3] + xv.w};
    *reinterpret_cast<float4*>(&z[idx]) = o;
  }
}

// ---- 11. per-node BN + relu + dot(w_out) -> out ----
__global__ __launch_bounds__(256) void k_final(const float* __restrict__ z,
                                               const float* __restrict__ g4,
                                               const float* __restrict__ b4v,
                                               const float* __restrict__ w_out,
                                               const float* __restrict__ b_out,
                                               float* __restrict__ out) {
  const int n = blockIdx.x;
  const int tid = threadIdx.x;
  float s = 0.f, s2 = 0.f;
#pragma unroll
  for (int it = 0; it < 8; ++it) {
    int e = it * 256 + tid;
    int b = e >> 7, c = e & 127;
    float v = z[(size_t)(b * kN + n) * kC + c];
    s += v; s2 += v * v;
  }
  for (int o = 32; o > 0; o >>= 1) { s += __shfl_down(s, o); s2 += __shfl_down(s2, o); }
  __shared__ float ls[4], ls2[4];
  __shared__ float sscale, sshift;
  const int w = tid >> 6;
  if ((tid & 63) == 0) { ls[w] = s; ls2[w] = s2; }
  __syncthreads();
  if (tid == 0) {
    float S = ls[0] + ls[1] + ls[2] + ls[3];
    float S2 = ls2[0] + ls2[1] + ls2[2] + ls2[3];
    float mean = S * (1.f / 2048.f);
    float var = S2 * (1.f / 2048.f) - mean * mean;
    var = fmaxf(var, 0.f);
    float inv = rsqrtf(var + kEPS);
    float gg = g4[n];
    sscale = inv * gg;
    sshift = b4v[n] - mean * inv * gg;
  }
  __syncthreads();
  const float scale = sscale, shift = sshift;
  const int b = tid >> 4, c0 = (tid & 15) * 8;
  float p = 0.f;
#pragma unroll
  for (int j = 0; j < 8; ++j) {
    float v = z[(size_t)(b * kN + n) * kC + c0 + j] * scale + shift;
    v = fmaxf(v, 0.f);
    p += v * w_out[c0 + j];
  }
  for (int o = 8; o > 0; o >>= 1) p += __shfl_down(p, o, 16);
  if ((tid & 15) == 0) out[b * kN + n] = p + b_out[0];
}

extern "C" void kernel_launch(void* const* d_in, const int* in_sizes, int n_in,
                              void* d_out, int out_size, void* d_ws, size_t ws_size,
                              hipStream_t stream) {
  const int*   data = (const int*)d_in[0];
  const float* node_features = (const float*)d_in[1];
  const float* go_adj = (const float*)d_in[2];
  const float* emb  = (const float*)d_in[4];
  const float* w_go = (const float*)d_in[5];
  const float* b_go = (const float*)d_in[6];
  const float* wq   = (const float*)d_in[7];
  const float* wk   = (const float*)d_in[8];
  const float* theta= (const float*)d_in[9];
  const float* g1   = (const float*)d_in[10];
  const float* b1   = (const float*)d_in[11];
  const float* g3   = (const float*)d_in[12];
  const float* b3   = (const float*)d_in[13];
  const float* g4   = (const float*)d_in[14];
  const float* b4   = (const float*)d_in[15];
  const float* w_out= (const float*)d_in[16];
  const float* b_out= (const float*)d_in[17];

  float* ws = (float*)d_ws;
  float* featpart = ws + OFF_FEATPART;
  float* m1t   = ws + OFF_M1;
  float* x     = ws + OFF_X;
  float* z     = ws + OFF_Z;
  float* tcur  = ws + OFF_TCUR;
  float* tnext = ws + OFF_TNEXT;
  float* gopart= ws + OFF_GOPART;
  float* pmax  = ws + OFF_PMAX;
  float* psum  = ws + OFF_PSUM;
  float* cmax  = ws + OFF_CMAX;
  float* cinv  = ws + OFF_CINV;
  ushort* adj_hi = (ushort*)(ws + OFF_ADJH);
  ushort* adj_lo = (ushort*)(ws + OFF_ADJL);
  ushort* xt_hi  = (ushort*)(ws + OFF_XTH);
  ushort* xt_lo  = (ushort*)(ws + OFF_XTL);
  ushort* qh     = (ushort*)(ws + OFF_QH);
  ushort* ql     = (ushort*)(ws + OFF_QL);
  ushort* kh     = (ushort*)(ws + OFF_KH);
  ushort* kl     = (ushort*)(ws + OFF_KL);

  k_embsum<<<dim3(16, 8), 256, 0, stream>>>(data, emb, featpart);
  k_bn_feat<<<1, 512, 0, stream>>>(featpart, data, g1, b1, m1t);
  k_go_gemm2<<<dim3(64, 4), 256, 0, stream>>>(m1t, w_go, gopart);
  k_go_reduce<<<1024, 256, 0, stream>>>(gopart, b_go, x);
  k_nf_bn<<<1024, 256, 0, stream>>>(node_features, g3, b3, x);
  k_qkgen<<<512, 256, 0, stream>>>(x, wq, wk, qh, ql, kh, kl);
  k_att_stats<<<dim3(16, 16), 512, 0, stream>>>(qh, ql, kh, kl, pmax, psum);
  k_soft_comb<<<64, 256, 0, stream>>>(pmax, psum, cmax, cinv);
  k_adj_emit<<<dim3(8, 16, 16), 512, 0, stream>>>(qh, ql, kh, kl, go_adj, cmax, cinv,
                                                  adj_hi, adj_lo);
  k_transp<<<dim3(16, 16), 256, 0, stream>>>(x, xt_hi, xt_lo);
  k_adjmm_mfma<<<256, 512, 0, stream>>>(adj_hi, adj_lo, xt_hi, xt_lo,
                                        nullptr, tcur, 1.0f);
  k_transp<<<dim3(16, 16), 256, 0, stream>>>(tcur, xt_hi, xt_lo);
  k_adjmm_mfma<<<256, 512, 0, stream>>>(adj_hi, adj_lo, xt_hi, xt_lo,
                                        x, tnext, 2.0f);
  k_theta<<<512, 256, 0, stream>>>(x, tcur, tnext, theta, z);
  k_final<<<1024, 256, 0, stream>>>(z, g4, b4, w_out, b_out, (float*)d_out);
}

// Round 6
// 240.226 us; speedup vs baseline: 1.7739x; 1.0405x over previous
//
#include <hip/hip_runtime.h>

namespace {
constexpr int kB = 16;
constexpr int kMAXLEN = 1024;
constexpr int kPE = 256;
constexpr int kN = 1024;
constexpr int kEMB = 256;
constexpr int kC = 128;
constexpr float kEPS = 1e-5f;

// workspace offsets in floats
constexpr size_t OFF_FEATPART = 0;                       // 16*16*256 = 65536
constexpr size_t OFF_M1       = 65536;                   // m1t: 512*16
constexpr size_t OFF_X        = 131072;                  // 16*1024*128
constexpr size_t OFF_Z        = OFF_X   + 2097152;       // theta output
constexpr size_t OFF_TCUR     = OFF_Z   + 2097152;
constexpr size_t OFF_TNEXT    = OFF_TCUR+ 2097152;
constexpr size_t OFF_GOPART   = OFF_TNEXT+2097152;       // 4*16*65536
constexpr size_t OFF_PMAX     = OFF_GOPART + 4194304;
constexpr size_t OFF_PSUM     = OFF_PMAX+ 262144;
constexpr size_t OFF_CMAX     = OFF_PSUM+ 262144;
constexpr size_t OFF_CINV     = OFF_CMAX+ 16384;
// bf16 buffers (float units)
constexpr size_t OFF_ADJH     = OFF_CINV + 16384;
constexpr size_t OFF_ADJL     = OFF_ADJH + 8388608;
constexpr size_t OFF_XTH      = OFF_ADJL + 8388608;      // x^T
constexpr size_t OFF_XTL      = OFF_XTH  + 1048576;
constexpr size_t OFF_QH       = OFF_XTL  + 1048576;
constexpr size_t OFF_QL       = OFF_QH   + 524288;
constexpr size_t OFF_KH       = OFF_QL   + 524288;
constexpr size_t OFF_KL       = OFF_KH   + 524288;
constexpr size_t OFF_TTH      = OFF_KL   + 524288;       // tcur^T
constexpr size_t OFF_TTL      = OFF_TTH  + 1048576;

typedef __attribute__((ext_vector_type(8))) short bfrag;
typedef __attribute__((ext_vector_type(4))) float f32x4;

__device__ inline ushort f2bf(float f) {
  unsigned u = __float_as_uint(f);
  unsigned r = (u + 0x7FFFu + ((u >> 16) & 1u)) >> 16;  // RNE
  return (ushort)r;
}
__device__ inline float bf2f(ushort h) { return __uint_as_float(((unsigned)h) << 16); }
} // namespace

// ---- 1. embedding gather partial sums: featpart[b][chunk16][e] ----
__global__ __launch_bounds__(256) void k_embsum(const int* __restrict__ data,
                                                const float* __restrict__ emb,
                                                float* __restrict__ featpart) {
  const int b = blockIdx.x, ch = blockIdx.y;   // 16 x 16
  const int e = threadIdx.x;                   // 256
  const int* row = data + b * (kMAXLEN + kPE) + ch * 64;
  float acc = 0.f;
#pragma unroll 4
  for (int l = 0; l < 64; ++l) {
    acc += emb[(size_t)row[l] * kEMB + e];
  }
  featpart[((b * 16 + ch) << 8) + e] = acc;
}

// ---- 2. BN over batch -> m1t (512,16) transposed ----
__global__ __launch_bounds__(512) void k_bn_feat(const float* __restrict__ featpart,
                                                 const int* __restrict__ data,
                                                 const float* __restrict__ g1,
                                                 const float* __restrict__ b1,
                                                 float* __restrict__ m1t) {
  const int j = threadIdx.x;
  float v[kB];
  if (j < kPE) {
    const float pe = sinf((float)j);
#pragma unroll
    for (int b = 0; b < kB; ++b) {
      float s = 0.f;
      for (int ch = 0; ch < 16; ++ch) s += featpart[((b * 16 + ch) << 8) + j];
      v[b] = s * (1.f / 1024.f) + pe;
    }
  } else {
    const int e = j - kPE;
    const float pe = sinf((float)e);
#pragma unroll
    for (int b = 0; b < kB; ++b)
      v[b] = (float)data[b * (kMAXLEN + kPE) + kMAXLEN + e] + pe;
  }
  float s = 0.f;
#pragma unroll
  for (int b = 0; b < kB; ++b) s += v[b];
  const float mean = s * (1.f / kB);
  float s2 = 0.f;
#pragma unroll
  for (int b = 0; b < kB; ++b) { float d = v[b] - mean; s2 += d * d; }
  const float inv = rsqrtf(s2 * (1.f / kB) + kEPS);
  const float g = g1[j], bb = b1[j];
#pragma unroll
  for (int b = 0; b < kB; ++b) m1t[j * kB + b] = (v[b] - mean) * inv * g + bb;
}

// ---- 3a. split-K GEMM (m1t via SGPR broadcast) ----
__global__ __launch_bounds__(256) void k_go_gemm2(const float* __restrict__ m1t,
                                                  const float* __restrict__ w_go,
                                                  float* __restrict__ part) {
  const int c0 = blockIdx.x * 1024 + threadIdx.x * 4;
  const int k0 = blockIdx.y * 128;
  float4 acc[kB];
#pragma unroll
  for (int b = 0; b < kB; ++b) acc[b] = make_float4(0.f, 0.f, 0.f, 0.f);
#pragma unroll 4
  for (int k = 0; k < 128; ++k) {
    const float4 w = *reinterpret_cast<const float4*>(&w_go[(size_t)(k0 + k) * 65536 + c0]);
    const float* mrow = m1t + (size_t)(k0 + k) * kB;
#pragma unroll
    for (int b = 0; b < kB; ++b) {
      const float m = mrow[b];
      acc[b].x += m * w.x; acc[b].y += m * w.y;
      acc[b].z += m * w.z; acc[b].w += m * w.w;
    }
  }
  const size_t kb16 = (size_t)blockIdx.y * kB;
#pragma unroll
  for (int b = 0; b < kB; ++b) {
    *reinterpret_cast<float4*>(&part[(kb16 + b) * 65536 + c0]) = acc[b];
  }
}

// ---- 3b+4 fused. per-node: reduce go partials + bias/relu, nf concat, BN, write x ----
__global__ __launch_bounds__(256) void k_go_bn(const float* __restrict__ part,
                                               const float* __restrict__ b_go,
                                               const float* __restrict__ nf,
                                               const float* __restrict__ g3,
                                               const float* __restrict__ b3,
                                               float* __restrict__ x) {
  const int n = blockIdx.x;
  const int tid = threadIdx.x;
  __shared__ float nfs[64];
  if (tid < 64) nfs[tid] = nf[n * 64 + tid];
  float val[4];
  float s = 0.f, s2 = 0.f;
#pragma unroll
  for (int i = 0; i < 4; ++i) {
    const int e = i * 256 + tid;
    const int b = e >> 6, c = e & 63;
    float a = part[(size_t)b * 65536 + n * 64 + c];
#pragma unroll
    for (int kb = 1; kb < 4; ++kb)
      a += part[(size_t)(kb * kB + b) * 65536 + n * 64 + c];
    a = fmaxf(a + b_go[n * 64 + c], 0.f);
    val[i] = a;
    s += a; s2 += a * a;
  }
  __syncthreads();
  if (tid < 64) {
    const float v = nfs[tid];
    s += 16.f * v; s2 += 16.f * v * v;
  }
  for (int o = 32; o > 0; o >>= 1) { s += __shfl_down(s, o); s2 += __shfl_down(s2, o); }
  __shared__ float ls[4], ls2[4];
  __shared__ float sscale, sshift;
  const int w = tid >> 6;
  if ((tid & 63) == 0) { ls[w] = s; ls2[w] = s2; }
  __syncthreads();
  if (tid == 0) {
    float S = ls[0] + ls[1] + ls[2] + ls[3];
    float S2 = ls2[0] + ls2[1] + ls2[2] + ls2[3];
    float mean = S * (1.f / 2048.f);
    float var = fmaxf(S2 * (1.f / 2048.f) - mean * mean, 0.f);
    float inv = rsqrtf(var + kEPS);
    float gg = g3[n];
    sscale = inv * gg;
    sshift = b3[n] - mean * inv * gg;
  }
  __syncthreads();
  const float scale = sscale, shift = sshift;
#pragma unroll
  for (int i = 0; i < 4; ++i) {
    const int e = i * 256 + tid;
    const int b = e >> 6, c = e & 63;
    x[((size_t)(b * kN + n)) * kC + c] = val[i] * scale + shift;
  }
#pragma unroll
  for (int i = 0; i < 4; ++i) {
    const int e = i * 256 + tid;
    const int b = e >> 6, c = e & 63;
    x[((size_t)(b * kN + n)) * kC + 64 + c] = nfs[c] * scale + shift;
  }
}

// ---- 5. q/k projections -> bf16 hi/lo, [bn][64] layout ----
__global__ __launch_bounds__(256) void k_qkgen(const float* __restrict__ x,
                                               const float* __restrict__ wq,
                                               const float* __restrict__ wk,
                                               ushort* __restrict__ qh, ushort* __restrict__ ql,
                                               ushort* __restrict__ kh, ushort* __restrict__ kl) {
  __shared__ float a_s[32 * 68];
  __shared__ float w_s[32 * 128];
  const int row0 = blockIdx.x * 32;
  const int tid = threadIdx.x;
  const int tr = tid >> 5, tc = tid & 31;
  const int r0 = tr * 4, c0 = tc * 4;
  float acc[4][4] = {};
  for (int kc = 0; kc < 4; ++kc) {
    const int k0 = kc * 32;
    __syncthreads();
    {
      int r = tid >> 3, kk4 = tid & 7;
      float4 v = *reinterpret_cast<const float4*>(&x[(size_t)(row0 + r) * kC + k0 + kk4 * 4]);
      *reinterpret_cast<float4*>(&a_s[r * 68 + kk4 * 4]) = v;
    }
    for (int it = 0; it < 16; ++it) {
      int e = it * 256 + tid;
      int kk = e >> 7, h2 = e & 127;
      int c = k0 + kk;
      float v = (h2 < 64) ? wq[c * 64 + h2] : wk[c * 64 + (h2 - 64)];
      w_s[kk * 128 + h2] = v;
    }
    __syncthreads();
#pragma unroll 8
    for (int k = 0; k < 32; ++k) {
      float a[4];
#pragma unroll
      for (int i = 0; i < 4; ++i) a[i] = a_s[(r0 + i) * 68 + k];
      float4 b4 = *reinterpret_cast<float4*>(&w_s[k * 128 + c0]);
      float bj[4] = {b4.x, b4.y, b4.z, b4.w};
#pragma unroll
      for (int i = 0; i < 4; ++i)
#pragma unroll
        for (int j = 0; j < 4; ++j) acc[i][j] += a[i] * bj[j];
    }
  }
  const bool isq = (c0 < 64);
  const int h0 = isq ? c0 : (c0 - 64);
  ushort* oh = isq ? qh : kh;
  ushort* ol = isq ? ql : kl;
#pragma unroll
  for (int i = 0; i < 4; ++i) {
    ushort hs[4], ls[4];
#pragma unroll
    for (int j = 0; j < 4; ++j) {
      float v = acc[i][j];
      ushort h = f2bf(v);
      hs[j] = h;
      ls[j] = f2bf(v - bf2f(h));
    }
    const size_t o = (size_t)(row0 + r0 + i) * 64 + h0;
    *reinterpret_cast<ushort4*>(&oh[o]) = *reinterpret_cast<ushort4*>(hs);
    *reinterpret_cast<ushort4*>(&ol[o]) = *reinterpret_cast<ushort4*>(ls);
  }
}

// ---- 6. att stats via MFMA: C[m][n] = K·Q^T, per-(b,nt) partial max/sum over n ----
__global__ __launch_bounds__(512) void k_att_stats(const ushort* __restrict__ qh,
                                                   const ushort* __restrict__ ql,
                                                   const ushort* __restrict__ kh,
                                                   const ushort* __restrict__ kl,
                                                   float* __restrict__ pmax,
                                                   float* __restrict__ psum) {
  const int nt = blockIdx.x, b = blockIdx.y;
  __shared__ uint4 smem4[3072];  // 48 KiB: Qh@0 Ql@8K Kh@16K Kl@32K
  char* smem = (char*)smem4;
  const int tid = threadIdx.x;
  const int lane = tid & 63, w = tid >> 6;
  const int l15 = lane & 15, lg = lane >> 4;

  {
    const int r = tid >> 3, ch = tid & 7;
    const size_t g = (size_t)(b * kN + nt * 64 + r) * 64 + ch * 8;
    const unsigned off = (unsigned)(r * 128 + ch * 16) ^ (unsigned)((r & 7) << 4);
    *reinterpret_cast<uint4*>(smem + off) = *reinterpret_cast<const uint4*>(qh + g);
    *reinterpret_cast<uint4*>(smem + 8192 + off) = *reinterpret_cast<const uint4*>(ql + g);
  }

  for (int mc = 0; mc < 8; ++mc) {
    __syncthreads();
#pragma unroll
    for (int p = 0; p < 2; ++p) {
      const int e = p * 512 + tid;
      const int c = e >> 3, ch = e & 7;
      const size_t g = (size_t)(b * kN + mc * 128 + c) * 64 + ch * 8;
      const unsigned off = (unsigned)(c * 128 + ch * 16) ^ (unsigned)((c & 7) << 4);
      *reinterpret_cast<uint4*>(smem + 16384 + off) = *reinterpret_cast<const uint4*>(kh + g);
      *reinterpret_cast<uint4*>(smem + 32768 + off) = *reinterpret_cast<const uint4*>(kl + g);
    }
    __syncthreads();
    f32x4 acc[4] = {{0.f,0.f,0.f,0.f},{0.f,0.f,0.f,0.f},{0.f,0.f,0.f,0.f},{0.f,0.f,0.f,0.f}};
#pragma unroll
    for (int ss = 0; ss < 2; ++ss) {
      const int r = w * 16 + l15;
      const unsigned aoff = (unsigned)(r * 128 + ss * 64 + lg * 16) ^ (unsigned)((r & 7) << 4);
      bfrag ah = *reinterpret_cast<const bfrag*>(smem + 16384 + aoff);
      bfrag al = *reinterpret_cast<const bfrag*>(smem + 32768 + aoff);
#pragma unroll
      for (int nf = 0; nf < 4; ++nf) {
        const int c = nf * 16 + l15;
        const unsigned boff = (unsigned)(c * 128 + ss * 64 + lg * 16) ^ (unsigned)((c & 7) << 4);
        bfrag bh = *reinterpret_cast<const bfrag*>(smem + boff);
        bfrag bl = *reinterpret_cast<const bfrag*>(smem + 8192 + boff);
        acc[nf] = __builtin_amdgcn_mfma_f32_16x16x32_bf16(ah, bh, acc[nf], 0, 0, 0);
        acc[nf] = __builtin_amdgcn_mfma_f32_16x16x32_bf16(ah, bl, acc[nf], 0, 0, 0);
        acc[nf] = __builtin_amdgcn_mfma_f32_16x16x32_bf16(al, bh, acc[nf], 0, 0, 0);
      }
    }
#pragma unroll
    for (int i = 0; i < 4; ++i) {
      float v0 = acc[0][i] * 0.125f, v1 = acc[1][i] * 0.125f;
      float v2 = acc[2][i] * 0.125f, v3 = acc[3][i] * 0.125f;
      float mx = fmaxf(fmaxf(v0, v1), fmaxf(v2, v3));
#pragma unroll
      for (int msk = 1; msk < 16; msk <<= 1) mx = fmaxf(mx, __shfl_xor(mx, msk));
      float sm = __expf(v0 - mx) + __expf(v1 - mx) + __expf(v2 - mx) + __expf(v3 - mx);
#pragma unroll
      for (int msk = 1; msk < 16; msk <<= 1) sm += __shfl_xor(sm, msk);
      if (l15 == 0) {
        const int m = mc * 128 + w * 16 + lg * 4 + i;
        const size_t o = (size_t)(b * 16 + nt) * kN + m;
        pmax[o] = mx;
        psum[o] = sm;
      }
    }
  }
}

// ---- 7. combine chunk stats -> colmax, 1/colsum ----
__global__ __launch_bounds__(256) void k_soft_comb(const float* __restrict__ pmax,
                                                   const float* __restrict__ psum,
                                                   float* __restrict__ cmax,
                                                   float* __restrict__ cinv) {
  const int i = blockIdx.x * 256 + threadIdx.x;
  const int b = i >> 10, m = i & 1023;
  float M = -1e30f;
#pragma unroll
  for (int c = 0; c < 16; ++c) M = fmaxf(M, pmax[(size_t)(b * 16 + c) * kN + m]);
  float S = 0.f;
#pragma unroll
  for (int c = 0; c < 16; ++c)
    S += psum[(size_t)(b * 16 + c) * kN + m] * __expf(pmax[(size_t)(b * 16 + c) * kN + m] - M);
  cmax[i] = M;
  cinv[i] = 1.f / S;
}

// ---- 8. adj emit: recompute Q·K^T, adj = go_adj + exp(.-M)*I -> bf16 hi/lo ----
__global__ __launch_bounds__(512) void k_adj_emit(const ushort* __restrict__ qh,
                                                  const ushort* __restrict__ ql,
                                                  const ushort* __restrict__ kh,
                                                  const ushort* __restrict__ kl,
                                                  const float* __restrict__ go_adj,
                                                  const float* __restrict__ cmax,
                                                  const float* __restrict__ cinv,
                                                  ushort* __restrict__ adj_hi,
                                                  ushort* __restrict__ adj_lo) {
  const int mc = blockIdx.x, nt = blockIdx.y, b = blockIdx.z;
  __shared__ uint4 smem4[3072];
  char* smem = (char*)smem4;
  float* c32 = (float*)smem4;
  const int tid = threadIdx.x;
  const int lane = tid & 63, w = tid >> 6;
  const int wr = w >> 2, wc = w & 3;
  const int l15 = lane & 15, lg = lane >> 4;

  {
    const int r = tid >> 3, ch = tid & 7;
    const size_t g = (size_t)(b * kN + nt * 64 + r) * 64 + ch * 8;
    const unsigned off = (unsigned)(r * 128 + ch * 16) ^ (unsigned)((r & 7) << 4);
    *reinterpret_cast<uint4*>(smem + off) = *reinterpret_cast<const uint4*>(qh + g);
    *reinterpret_cast<uint4*>(smem + 8192 + off) = *reinterpret_cast<const uint4*>(ql + g);
  }
#pragma unroll
  for (int p = 0; p < 2; ++p) {
    const int e = p * 512 + tid;
    const int c = e >> 3, ch = e & 7;
    const size_t g = (size_t)(b * kN + mc * 128 + c) * 64 + ch * 8;
    const unsigned off = (unsigned)(c * 128 + ch * 16) ^ (unsigned)((c & 7) << 4);
    *reinterpret_cast<uint4*>(smem + 16384 + off) = *reinterpret_cast<const uint4*>(kh + g);
    *reinterpret_cast<uint4*>(smem + 32768 + off) = *reinterpret_cast<const uint4*>(kl + g);
  }
  __syncthreads();
  f32x4 acc[2][2] = {{{0.f,0.f,0.f,0.f},{0.f,0.f,0.f,0.f}},
                     {{0.f,0.f,0.f,0.f},{0.f,0.f,0.f,0.f}}};
#pragma unroll
  for (int ss = 0; ss < 2; ++ss) {
    bfrag ah[2], al[2], bh[2], bl[2];
#pragma unroll
    for (int nf = 0; nf < 2; ++nf) {
      const int r = wr * 32 + nf * 16 + l15;
      const unsigned aoff = (unsigned)(r * 128 + ss * 64 + lg * 16) ^ (unsigned)((r & 7) << 4);
      ah[nf] = *reinterpret_cast<const bfrag*>(smem + aoff);
      al[nf] = *reinterpret_cast<const bfrag*>(smem + 8192 + aoff);
    }
#pragma unroll
    for (int mf = 0; mf < 2; ++mf) {
      const int c = wc * 32 + mf * 16 + l15;
      const unsigned boff = (unsigned)(c * 128 + ss * 64 + lg * 16) ^ (unsigned)((c & 7) << 4);
      bh[mf] = *reinterpret_cast<const bfrag*>(smem + 16384 + boff);
      bl[mf] = *reinterpret_cast<const bfrag*>(smem + 32768 + boff);
    }
#pragma unroll
    for (int nf = 0; nf < 2; ++nf)
#pragma unroll
      for (int mf = 0; mf < 2; ++mf) {
        acc[nf][mf] = __builtin_amdgcn_mfma_f32_16x16x32_bf16(ah[nf], bh[mf], acc[nf][mf], 0, 0, 0);
        acc[nf][mf] = __builtin_amdgcn_mfma_f32_16x16x32_bf16(ah[nf], bl[mf], acc[nf][mf], 0, 0, 0);
        acc[nf][mf] = __builtin_amdgcn_mfma_f32_16x16x32_bf16(al[nf], bh[mf], acc[nf][mf], 0, 0, 0);
      }
  }
  __syncthreads();
#pragma unroll
  for (int mf = 0; mf < 2; ++mf) {
    const int mLoc = wc * 32 + mf * 16 + l15;
    const int mG = b * kN + mc * 128 + mLoc;
    const float M = cmax[mG], I = cinv[mG];
#pragma unroll
    for (int nf = 0; nf < 2; ++nf) {
#pragma unroll
      for (int i = 0; i < 4; ++i) {
        const int nLoc = wr * 32 + nf * 16 + lg * 4 + i;
        c32[nLoc * 132 + mLoc] = __expf(acc[nf][mf][i] * 0.125f - M) * I;
      }
    }
  }
  __syncthreads();
#pragma unroll
  for (int p = 0; p < 2; ++p) {
    const int e = p * 512 + tid;
    const int n = e >> 4, m0 = (e & 15) * 8;
    const float* cr = &c32[n * 132 + m0];
    const float* ga = &go_adj[(size_t)(nt * 64 + n) * kN + mc * 128 + m0];
    ushort hs[8], ls[8];
#pragma unroll
    for (int j = 0; j < 8; ++j) {
      float v = cr[j] + ga[j];
      ushort h = f2bf(v);
      hs[j] = h;
      ls[j] = f2bf(v - bf2f(h));
    }
    const size_t o = (size_t)(b * kN + nt * 64 + n) * kN + mc * 128 + m0;
    *reinterpret_cast<uint4*>(&adj_hi[o]) = *reinterpret_cast<uint4*>(hs);
    *reinterpret_cast<uint4*>(&adj_lo[o]) = *reinterpret_cast<uint4*>(ls);
  }
}

// ---- T. transpose+split: f32 [16][1024][128] -> bf16 hi/lo [16][128][1024] ----
__global__ __launch_bounds__(256) void k_transp(const float* __restrict__ src,
                                                ushort* __restrict__ xt_hi,
                                                ushort* __restrict__ xt_lo) {
  const int nt = blockIdx.x, b = blockIdx.y;
  __shared__ float tile[64][133];
  const int tid = threadIdx.x;
#pragma unroll
  for (int it = 0; it < 8; ++it) {
    int e = it * 256 + tid;
    int r = e >> 5, c4 = e & 31;
    float4 v = *reinterpret_cast<const float4*>(&src[(size_t)(b * kN + nt * 64 + r) * kC + c4 * 4]);
    *reinterpret_cast<float4*>(&tile[r][c4 * 4]) = v;
  }
  __syncthreads();
  const int cl = tid >> 3;
  const int chunk = tid & 7;
  const int n0 = chunk * 8;
#pragma unroll
  for (int cg = 0; cg < 4; ++cg) {
    const int c = cg * 32 + cl;
    const size_t obase = (size_t)(b * kC + c) * kN + nt * 64 + n0;
    ushort hs[8], ls[8];
#pragma unroll
    for (int j = 0; j < 8; ++j) {
      float v = tile[n0 + j][c];
      ushort h = f2bf(v);
      hs[j] = h;
      ls[j] = f2bf(v - bf2f(h));
    }
    *reinterpret_cast<uint4*>(&xt_hi[obase]) = *reinterpret_cast<uint4*>(hs);
    *reinterpret_cast<uint4*>(&xt_lo[obase]) = *reinterpret_cast<uint4*>(ls);
  }
}

// ---- 9. Y = alpha * adj @ X (- Zsub); optional transposed bf16 emit ----
// grid 256 (xcd-swizzled), block 512 = 8 waves. BM=64, BN=128, BK=64.
__global__ __launch_bounds__(512) void k_adjmm_mfma(const ushort* __restrict__ adj_hi,
                                                    const ushort* __restrict__ adj_lo,
                                                    const ushort* __restrict__ xt_hi,
                                                    const ushort* __restrict__ xt_lo,
                                                    const float* __restrict__ Zsub,
                                                    float* __restrict__ Y, float alpha,
                                                    ushort* __restrict__ yt_hi,
                                                    ushort* __restrict__ yt_lo) {
  const int bid = blockIdx.x;
  const int swz = (bid & 7) * 32 + (bid >> 3);
  const int b = swz >> 4, rb = swz & 15;
  __shared__ uint4 smem4[3072];
  char* smem = (char*)smem4;
  float* c32 = (float*)smem4;   // [64][132] overlay in epilogue
  const int tid = threadIdx.x;
  const int lane = tid & 63, w = tid >> 6;
  const int wr = w >> 1, wc = w & 1;
  const int l15 = lane & 15, lg = lane >> 4;

  f32x4 acc[4] = {{0.f,0.f,0.f,0.f},{0.f,0.f,0.f,0.f},{0.f,0.f,0.f,0.f},{0.f,0.f,0.f,0.f}};
  const size_t adjrow0 = (size_t)b * kN + rb * 64;

  for (int kt = 0; kt < 16; ++kt) {
    const int k0 = kt * 64;
    __syncthreads();
    {
      const int r = tid >> 3, ch = tid & 7;
      const size_t g = (adjrow0 + r) * kN + k0 + ch * 8;
      const unsigned off = (unsigned)(r * 128 + ch * 16) ^ (unsigned)((r & 7) << 4);
      *reinterpret_cast<uint4*>(smem + off) = *reinterpret_cast<const uint4*>(adj_hi + g);
      *reinterpret_cast<uint4*>(smem + 8192 + off) = *reinterpret_cast<const uint4*>(adj_lo + g);
    }
#pragma unroll
    for (int p = 0; p < 2; ++p) {
      const int e = p * 512 + tid;
      const int c = e >> 3, ch = e & 7;
      const size_t g = ((size_t)b * kC + c) * kN + k0 + ch * 8;
      const unsigned off = (unsigned)(c * 128 + ch * 16) ^ (unsigned)((c & 7) << 4);
      *reinterpret_cast<uint4*>(smem + 16384 + off) = *reinterpret_cast<const uint4*>(xt_hi + g);
      *reinterpret_cast<uint4*>(smem + 32768 + off) = *reinterpret_cast<const uint4*>(xt_lo + g);
    }
    __syncthreads();
#pragma unroll
    for (int ss = 0; ss < 2; ++ss) {
      const int r = wr * 16 + l15;
      const unsigned aoff = (unsigned)(r * 128 + ss * 64 + lg * 16) ^ (unsigned)((r & 7) << 4);
      bfrag ah = *reinterpret_cast<const bfrag*>(smem + aoff);
      bfrag al = *reinterpret_cast<const bfrag*>(smem + 8192 + aoff);
      bfrag bh[4], bl[4];
#pragma unroll
      for (int ct = 0; ct < 4; ++ct) {
        const int c = wc * 64 + ct * 16 + l15;
        const unsigned boff = (unsigned)(c * 128 + ss * 64 + lg * 16) ^ (unsigned)((c & 7) << 4);
        bh[ct] = *reinterpret_cast<const bfrag*>(smem + 16384 + boff);
        bl[ct] = *reinterpret_cast<const bfrag*>(smem + 32768 + boff);
      }
#pragma unroll
      for (int ct = 0; ct < 4; ++ct) {
        acc[ct] = __builtin_amdgcn_mfma_f32_16x16x32_bf16(ah, bh[ct], acc[ct], 0, 0, 0);
        acc[ct] = __builtin_amdgcn_mfma_f32_16x16x32_bf16(ah, bl[ct], acc[ct], 0, 0, 0);
        acc[ct] = __builtin_amdgcn_mfma_f32_16x16x32_bf16(al, bh[ct], acc[ct], 0, 0, 0);
      }
    }
  }
  const int orow = rb * 64 + wr * 16 + lg * 4;
  __syncthreads();  // all LDS reads done before c32 overlay
#pragma unroll
  for (int ct = 0; ct < 4; ++ct) {
    const int ocol = wc * 64 + ct * 16 + l15;
#pragma unroll
    for (int i = 0; i < 4; ++i) {
      const size_t idx = ((size_t)(b * kN + orow + i)) * kC + ocol;
      float v = alpha * acc[ct][i];
      if (Zsub) v -= Zsub[idx];
      Y[idx] = v;
      if (yt_hi) c32[(wr * 16 + lg * 4 + i) * 132 + ocol] = v;
    }
  }
  if (yt_hi) {
    __syncthreads();
    // write Y^T: [b][c][rb*64 + n], 16 n per thread
    const int c = tid >> 2, nch = tid & 3;
    const int n0 = nch * 16;
    ushort hs[16], ls[16];
#pragma unroll
    for (int j = 0; j < 16; ++j) {
      float v = c32[(n0 + j) * 132 + c];
      ushort h = f2bf(v);
      hs[j] = h;
      ls[j] = f2bf(v - bf2f(h));
    }
    const size_t obase = (size_t)(b * kC + c) * kN + rb * 64 + n0;
    *reinterpret_cast<uint4*>(&yt_hi[obase]) = *reinterpret_cast<uint4*>(hs);
    *reinterpret_cast<uint4*>(&yt_hi[obase + 8]) = *reinterpret_cast<uint4*>(hs + 8);
    *reinterpret_cast<uint4*>(&yt_lo[obase]) = *reinterpret_cast<uint4*>(ls);
    *reinterpret_cast<uint4*>(&yt_lo[obase + 8]) = *reinterpret_cast<uint4*>(ls + 8);
  }
}

// ---- 10. z = x@th0 + tcur@th1 + tnext@th2 + x ----
__global__ __launch_bounds__(256) void k_theta(const float* __restrict__ x,
                                               const float* __restrict__ tcur,
                                               const float* __restrict__ tnext,
                                               const float* __restrict__ theta,
                                               float* __restrict__ z) {
  __shared__ float a_s[32 * 68];
  __shared__ float w_s[32 * 128];
  const int row0 = blockIdx.x * 32;
  const int tid = threadIdx.x;
  const int tr = tid >> 5, tc = tid & 31;
  const int r0 = tr * 4, c0 = tc * 4;
  float acc[4][4] = {};
  const float* srcs[3] = {x, tcur, tnext};
  for (int s = 0; s < 3; ++s) {
    const float* A = srcs[s];
    for (int kc = 0; kc < 4; ++kc) {
      const int k0 = kc * 32;
      __syncthreads();
      {
        int r = tid >> 3, kk4 = tid & 7;
        float4 v = *reinterpret_cast<const float4*>(&A[(size_t)(row0 + r) * kC + k0 + kk4 * 4]);
        *reinterpret_cast<float4*>(&a_s[r * 68 + kk4 * 4]) = v;
      }
#pragma unroll
      for (int it = 0; it < 4; ++it) {
        int e4 = it * 256 + tid;
        int kk = e4 >> 5, d4 = e4 & 31;
        float4 v = *reinterpret_cast<const float4*>(
            &theta[(size_t)s * 16384 + (size_t)(k0 + kk) * kC + d4 * 4]);
        *reinterpret_cast<float4*>(&w_s[kk * 128 + d4 * 4]) = v;
      }
      __syncthreads();
#pragma unroll 8
      for (int k = 0; k < 32; ++k) {
        float a[4];
#pragma unroll
        for (int i = 0; i < 4; ++i) a[i] = a_s[(r0 + i) * 68 + k];
        float4 b4 = *reinterpret_cast<float4*>(&w_s[k * 128 + c0]);
        float bj[4] = {b4.x, b4.y, b4.z, b4.w};
#pragma unroll
        for (int i = 0; i < 4; ++i)
#pragma unroll
          for (int j = 0; j < 4; ++j) acc[i][j] += a[i] * bj[j];
      }
    }
  }
#pragma unroll
  for (int i = 0; i < 4; ++i) {
    size_t idx = (size_t)(row0 + r0 + i) * kC + c0;
    float4 xv = *reinterpret_cast<const float4*>(&x[idx]);
    float4 o = {acc[i][0] + xv.x, acc[i][1] + xv.y, acc[i][2] + xv.z, acc[i][3] + xv.w};
    *reinterpret_cast<float4*>(&z[idx]) = o;
  }
}

// ---- 11. per-node BN + relu + dot(w_out) -> out ----
__global__ __launch_bounds__(256) void k_final(const float* __restrict__ z,
                                               const float* __restrict__ g4,
                                               const float* __restrict__ b4v,
                                               const float* __restrict__ w_out,
                                               const float* __restrict__ b_out,
                                               float* __restrict__ out) {
  const int n = blockIdx.x;
  const int tid = threadIdx.x;
  float s = 0.f, s2 = 0.f;
#pragma unroll
  for (int it = 0; it < 8; ++it) {
    int e = it * 256 + tid;
    int b = e >> 7, c = e & 127;
    float v = z[(size_t)(b * kN + n) * kC + c];
    s += v; s2 += v * v;
  }
  for (int o = 32; o > 0; o >>= 1) { s += __shfl_down(s, o); s2 += __shfl_down(s2, o); }
  __shared__ float ls[4], ls2[4];
  __shared__ float sscale, sshift;
  const int w = tid >> 6;
  if ((tid & 63) == 0) { ls[w] = s; ls2[w] = s2; }
  __syncthreads();
  if (tid == 0) {
    float S = ls[0] + ls[1] + ls[2] + ls[3];
    float S2 = ls2[0] + ls2[1] + ls2[2] + ls2[3];
    float mean = S * (1.f / 2048.f);
    float var = fmaxf(S2 * (1.f / 2048.f) - mean * mean, 0.f);
    float inv = rsqrtf(var + kEPS);
    float gg = g4[n];
    sscale = inv * gg;
    sshift = b4v[n] - mean * inv * gg;
  }
  __syncthreads();
  const float scale = sscale, shift = sshift;
  const int b = tid >> 4, c0 = (tid & 15) * 8;
  float p = 0.f;
#pragma unroll
  for (int j = 0; j < 8; ++j) {
    float v = z[(size_t)(b * kN + n) * kC + c0 + j] * scale + shift;
    v = fmaxf(v, 0.f);
    p += v * w_out[c0 + j];
  }
  for (int o = 8; o > 0; o >>= 1) p += __shfl_down(p, o, 16);
  if ((tid & 15) == 0) out[b * kN + n] = p + b_out[0];
}

extern "C" void kernel_launch(void* const* d_in, const int* in_sizes, int n_in,
                              void* d_out, int out_size, void* d_ws, size_t ws_size,
                              hipStream_t stream) {
  const int*   data = (const int*)d_in[0];
  const float* node_features = (const float*)d_in[1];
  const float* go_adj = (const float*)d_in[2];
  const float* emb  = (const float*)d_in[4];
  const float* w_go = (const float*)d_in[5];
  const float* b_go = (const float*)d_in[6];
  const float* wq   = (const float*)d_in[7];
  const float* wk   = (const float*)d_in[8];
  const float* theta= (const float*)d_in[9];
  const float* g1   = (const float*)d_in[10];
  const float* b1   = (const float*)d_in[11];
  const float* g3   = (const float*)d_in[12];
  const float* b3   = (const float*)d_in[13];
  const float* g4   = (const float*)d_in[14];
  const float* b4   = (const float*)d_in[15];
  const float* w_out= (const float*)d_in[16];
  const float* b_out= (const float*)d_in[17];

  float* ws = (float*)d_ws;
  float* featpart = ws + OFF_FEATPART;
  float* m1t   = ws + OFF_M1;
  float* x     = ws + OFF_X;
  float* z     = ws + OFF_Z;
  float* tcur  = ws + OFF_TCUR;
  float* tnext = ws + OFF_TNEXT;
  float* gopart= ws + OFF_GOPART;
  float* pmax  = ws + OFF_PMAX;
  float* psum  = ws + OFF_PSUM;
  float* cmax  = ws + OFF_CMAX;
  float* cinv  = ws + OFF_CINV;
  ushort* adj_hi = (ushort*)(ws + OFF_ADJH);
  ushort* adj_lo = (ushort*)(ws + OFF_ADJL);
  ushort* xt_hi  = (ushort*)(ws + OFF_XTH);
  ushort* xt_lo  = (ushort*)(ws + OFF_XTL);
  ushort* qh     = (ushort*)(ws + OFF_QH);
  ushort* ql     = (ushort*)(ws + OFF_QL);
  ushort* kh     = (ushort*)(ws + OFF_KH);
  ushort* kl     = (ushort*)(ws + OFF_KL);
  ushort* tth    = (ushort*)(ws + OFF_TTH);
  ushort* ttl    = (ushort*)(ws + OFF_TTL);

  k_embsum<<<dim3(16, 16), 256, 0, stream>>>(data, emb, featpart);
  k_bn_feat<<<1, 512, 0, stream>>>(featpart, data, g1, b1, m1t);
  k_go_gemm2<<<dim3(64, 4), 256, 0, stream>>>(m1t, w_go, gopart);
  k_go_bn<<<1024, 256, 0, stream>>>(gopart, b_go, node_features, g3, b3, x);
  k_qkgen<<<512, 256, 0, stream>>>(x, wq, wk, qh, ql, kh, kl);
  k_att_stats<<<dim3(16, 16), 512, 0, stream>>>(qh, ql, kh, kl, pmax, psum);
  k_soft_comb<<<64, 256, 0, stream>>>(pmax, psum, cmax, cinv);
  k_adj_emit<<<dim3(8, 16, 16), 512, 0, stream>>>(qh, ql, kh, kl, go_adj, cmax, cinv,
                                                  adj_hi, adj_lo);
  k_transp<<<dim3(16, 16), 256, 0, stream>>>(x, xt_hi, xt_lo);
  k_adjmm_mfma<<<256, 512, 0, stream>>>(adj_hi, adj_lo, xt_hi, xt_lo,
                                        nullptr, tcur, 1.0f, tth, ttl);
  k_adjmm_mfma<<<256, 512, 0, stream>>>(adj_hi, adj_lo, tth, ttl,
                                        x, tnext, 2.0f, nullptr, nullptr);
  k_theta<<<512, 256, 0, stream>>>(x, tcur, tnext, theta, z);
  k_final<<<1024, 256, 0, stream>>>(z, g4, b4, w_out, b_out, (float*)d_out);
}